// Round 9
// baseline (389.378 us; speedup 1.0000x reference)
//
#include <hip/hip_runtime.h>
#include <hip/hip_bf16.h>
#include <math.h>

// Problem constants (from reference)
#define Bb 32
#define Vv 50
#define Cc 64
#define Ee 256
#define Aa 128
#define Hh 256
#define Ll 10
#define BVn (Bb*Vv)          // 1600
#define SCALE 0.08838834764831845f   // 1/sqrt(128)

// persistent-LSTM config
#define NB 8          // blocks
#define HS 32         // hidden units per block
#define RWS (4*HS)    // gate rows per block = 128
#define WPAD 264      // bf16 row stride
#define GPAD 132      // f32 row stride for gates scratch
#define CPAD 36       // f32 row stride for c state
#define FSTR 64       // flag stride in u32 (256 B -> one cache line per flag)

// attn LDS strides (bf16 elements)
#define EPAD 264
#define QPAD 136

typedef __bf16 bf16x8 __attribute__((ext_vector_type(8)));
typedef float  f32x4  __attribute__((ext_vector_type(4)));

__device__ __forceinline__ float sigmoidf_(float x) {
    return 1.0f / (1.0f + __expf(-x));
}
__device__ __forceinline__ float tanhf_(float x) {
    return 1.0f - 2.0f / (__expf(2.0f * x) + 1.0f);
}

// ---------------------------------------------------------------------------
// Kernel 0: decompose WQ1/WK1 into bf16 hi/lo pairs; block 0 zeroes sync flags
// ---------------------------------------------------------------------------
__global__ __launch_bounds__(256) void wsplit(
    const float* __restrict__ wq, const float* __restrict__ wk,
    __bf16* __restrict__ qh, __bf16* __restrict__ ql,
    __bf16* __restrict__ kh, __bf16* __restrict__ kl,
    unsigned* __restrict__ flags)
{
    if (blockIdx.x == 0) {
        for (int i = threadIdx.x; i < NB * FSTR; i += 256)
            __hip_atomic_store(&flags[i], 0u, __ATOMIC_RELAXED,
                               __HIP_MEMORY_SCOPE_AGENT);
    }
    int i = blockIdx.x * 256 + threadIdx.x;    // 0..65535
    if (i < 32768) {
        float f = wq[i];
        __bf16 h = (__bf16)f;
        qh[i] = h; ql[i] = (__bf16)(f - (float)h);
    } else {
        int j = i - 32768;
        float f = wk[j];
        __bf16 h = (__bf16)f;
        kh[j] = h; kl[j] = (__bf16)(f - (float)h);
    }
}

// ---------------------------------------------------------------------------
// Kernel 1: attention — split-bf16 MFMA, in-register softmax. (unchanged r6)
// ---------------------------------------------------------------------------
__global__ __launch_bounds__(256, 2) void attn_v2(
    const int*   __restrict__ codes,
    const float* __restrict__ mask,
    const float* __restrict__ tvals,
    const float* __restrict__ emb_table,
    const __bf16* __restrict__ wqhi, const __bf16* __restrict__ wqlo,
    const __bf16* __restrict__ wkhi, const __bf16* __restrict__ wklo,
    const float* __restrict__ decay,
    const float* __restrict__ initial,
    float*       __restrict__ vv)
{
    __shared__ __align__(16) __bf16 buf[4 * Cc * QPAD];
    __shared__ int   codes_l[Cc];
    __shared__ float maskcol_s[Cc], coef_s[Cc], wsum_s[Cc];
    __shared__ float wpart[4][Cc];

    __bf16* ehi = buf;
    __bf16* elo = buf + Cc * EPAD;
    __bf16* qhi = buf;
    __bf16* qlo = buf + 1 * Cc * QPAD;
    __bf16* khi = buf + 2 * Cc * QPAD;
    __bf16* klo = buf + 3 * Cc * QPAD;

    const int n   = blockIdx.x;
    const int tid = threadIdx.x;
    const int b   = n / Vv;
    const int v   = n - b * Vv;
    const int wv  = tid >> 6;
    const int lane = tid & 63;
    const int lr  = lane & 15;
    const int lq  = lane >> 4;

    if (tid < Cc) {
        codes_l[tid]   = codes[n * Cc + tid];
        maskcol_s[tid] = mask[n * Cc + tid];
    }
    __syncthreads();

    for (int i = tid; i < Cc * Ee; i += 256) {
        int c = i >> 8, e = i & 255;
        float f = emb_table[(size_t)codes_l[c] * Ee + e];
        __bf16 h = (__bf16)f;
        ehi[c * EPAD + e] = h;
        elo[c * EPAD + e] = (__bf16)(f - (float)h);
    }
    if (tid < Cc) {
        int code = codes_l[tid];
        float keep = (maskcol_s[tid] == 0.0f) ? 1.0f : 0.0f;
        coef_s[tid] = keep * sigmoidf_(decay[code] * tvals[n] + initial[code]);
    }
    __syncthreads();

    const __bf16* bh = (wv < 2) ? wqhi : wkhi;
    const __bf16* bl = (wv < 2) ? wqlo : wklo;
    const int colbase = (wv & 1) * 64;

    f32x4 acc[4][4] = {};
    for (int kt = 0; kt < 8; ++kt) {
        const int k0 = kt * 32 + lq * 8;
        bf16x8 Ahh[4], All[4], Bhh[4], Bll[4];
#pragma unroll
        for (int mf = 0; mf < 4; ++mf) {
            Ahh[mf] = *(const bf16x8*)&ehi[(mf * 16 + lr) * EPAD + k0];
            All[mf] = *(const bf16x8*)&elo[(mf * 16 + lr) * EPAD + k0];
        }
#pragma unroll
        for (int nf = 0; nf < 4; ++nf) {
            const int row = colbase + nf * 16 + lr;
            Bhh[nf] = *(const bf16x8*)&bh[row * Ee + k0];
            Bll[nf] = *(const bf16x8*)&bl[row * Ee + k0];
        }
#pragma unroll
        for (int mf = 0; mf < 4; ++mf)
#pragma unroll
            for (int nf = 0; nf < 4; ++nf) {
                acc[mf][nf] = __builtin_amdgcn_mfma_f32_16x16x32_bf16(Ahh[mf], Bhh[nf], acc[mf][nf], 0, 0, 0);
                acc[mf][nf] = __builtin_amdgcn_mfma_f32_16x16x32_bf16(Ahh[mf], Bll[nf], acc[mf][nf], 0, 0, 0);
                acc[mf][nf] = __builtin_amdgcn_mfma_f32_16x16x32_bf16(All[mf], Bhh[nf], acc[mf][nf], 0, 0, 0);
            }
    }
    __syncthreads();

    {
        __bf16* dh = (wv < 2) ? qhi : khi;
        __bf16* dl = (wv < 2) ? qlo : klo;
#pragma unroll
        for (int mf = 0; mf < 4; ++mf)
#pragma unroll
            for (int nf = 0; nf < 4; ++nf) {
                const int colb = colbase + nf * 16 + lr;
#pragma unroll
                for (int r = 0; r < 4; ++r) {
                    const int m = mf * 16 + lq * 4 + r;
                    float q = acc[mf][nf][r];
                    __bf16 h = (__bf16)q;
                    dh[m * QPAD + colb] = h;
                    dl[m * QPAD + colb] = (__bf16)(q - (float)h);
                }
            }
    }
    __syncthreads();

    f32x4 dacc[4] = {};
    for (int kt = 0; kt < 4; ++kt) {
        const int k0 = kt * 32 + lq * 8;
        bf16x8 Ahh = *(const bf16x8*)&qhi[(wv * 16 + lr) * QPAD + k0];
        bf16x8 All = *(const bf16x8*)&qlo[(wv * 16 + lr) * QPAD + k0];
#pragma unroll
        for (int nf = 0; nf < 4; ++nf) {
            bf16x8 Bhh = *(const bf16x8*)&khi[(nf * 16 + lr) * QPAD + k0];
            bf16x8 Bll = *(const bf16x8*)&klo[(nf * 16 + lr) * QPAD + k0];
            dacc[nf] = __builtin_amdgcn_mfma_f32_16x16x32_bf16(Ahh, Bhh, dacc[nf], 0, 0, 0);
            dacc[nf] = __builtin_amdgcn_mfma_f32_16x16x32_bf16(Ahh, Bll, dacc[nf], 0, 0, 0);
            dacc[nf] = __builtin_amdgcn_mfma_f32_16x16x32_bf16(All, Bhh, dacc[nf], 0, 0, 0);
        }
    }

    float p[4][4], inv[4];
#pragma unroll
    for (int r = 0; r < 4; ++r) {
#pragma unroll
        for (int nf = 0; nf < 4; ++nf)
            p[r][nf] = (dacc[nf][r] - maskcol_s[nf * 16 + lr]) * SCALE;
        float mx = fmaxf(fmaxf(p[r][0], p[r][1]), fmaxf(p[r][2], p[r][3]));
        mx = fmaxf(mx, __shfl_xor(mx, 1));
        mx = fmaxf(mx, __shfl_xor(mx, 2));
        mx = fmaxf(mx, __shfl_xor(mx, 4));
        mx = fmaxf(mx, __shfl_xor(mx, 8));
        float s = 0.f;
#pragma unroll
        for (int nf = 0; nf < 4; ++nf) { p[r][nf] = __expf(p[r][nf] - mx); s += p[r][nf]; }
        s += __shfl_xor(s, 1);
        s += __shfl_xor(s, 2);
        s += __shfl_xor(s, 4);
        s += __shfl_xor(s, 8);
        inv[r] = 1.0f / s;
    }

    float part[4];
#pragma unroll
    for (int nf = 0; nf < 4; ++nf) {
        float a = 0.f;
#pragma unroll
        for (int r = 0; r < 4; ++r) {
            const int row = wv * 16 + lq * 4 + r;
            a = fmaf(coef_s[row] * inv[r], p[r][nf], a);
        }
        part[nf] = a;
    }
#pragma unroll
    for (int nf = 0; nf < 4; ++nf) {
        part[nf] += __shfl_xor(part[nf], 16);
        part[nf] += __shfl_xor(part[nf], 32);
    }
    if (lq == 0)
#pragma unroll
        for (int nf = 0; nf < 4; ++nf) wpart[wv][nf * 16 + lr] = part[nf];
    __syncthreads();
    if (tid < Cc)
        wsum_s[tid] = wpart[0][tid] + wpart[1][tid] + wpart[2][tid] + wpart[3][tid];
    __syncthreads();

    float a3 = 0.f;
#pragma unroll 8
    for (int d = 0; d < Cc; ++d)
        a3 = fmaf(wsum_s[d], emb_table[(size_t)codes_l[d] * Ee + tid], a3);
    vv[(v * Bb + b) * Ee + tid] = a3;
}

// ---------------------------------------------------------------------------
// Kernel 2: merged fwd+bwd x@W^T. blockIdx.x<25 -> forward; ==25 -> backward.
// ---------------------------------------------------------------------------
__global__ __launch_bounds__(256) void xw_kernel(
    const float* __restrict__ vv,
    const float* __restrict__ w_ih_f, const float* __restrict__ b_ih_f,
    const float* __restrict__ b_hh_f,
    const float* __restrict__ w_ih_b, const float* __restrict__ b_ih_b,
    const float* __restrict__ b_hh_b,
    float* __restrict__ xg_f, float* __restrict__ xgb)
{
    const bool bwd = (blockIdx.x == 25);
    const float* A  = bwd ? (vv + 49 * Bb * Ee) : vv;
    const float* W  = bwd ? w_ih_b : w_ih_f;
    const float* b1 = bwd ? b_ih_b : b_ih_f;
    const float* b2 = bwd ? b_hh_b : b_hh_f;
    float* Cout     = bwd ? xgb : xg_f;
    const int M     = bwd ? Bb : BVn;
    const int m0    = bwd ? 0 : blockIdx.x * 64;
    const int j0    = blockIdx.y * 64;

    __shared__ float a_s[64 * 65];
    __shared__ float w_s[64 * 65];
    const int tid = threadIdx.x, tx = tid & 15, ty = tid >> 4;
    float acc[4][4] = {};
    for (int kc = 0; kc < 256; kc += 64) {
        __syncthreads();
        for (int idx = tid; idx < 4096; idx += 256) {
            int r = idx >> 6, kk = idx & 63;
            int m = m0 + r;
            a_s[r * 65 + kk] = (m < M) ? A[m * 256 + kc + kk] : 0.f;
            w_s[r * 65 + kk] = W[(j0 + r) * 256 + kc + kk];
        }
        __syncthreads();
#pragma unroll 8
        for (int kk = 0; kk < 64; ++kk) {
            float av[4], wv[4];
#pragma unroll
            for (int i = 0; i < 4; ++i) av[i] = a_s[(ty * 4 + i) * 65 + kk];
#pragma unroll
            for (int j = 0; j < 4; ++j) wv[j] = w_s[(tx * 4 + j) * 65 + kk];
#pragma unroll
            for (int i = 0; i < 4; ++i)
#pragma unroll
                for (int j = 0; j < 4; ++j)
                    acc[i][j] = fmaf(av[i], wv[j], acc[i][j]);
        }
    }
#pragma unroll
    for (int i = 0; i < 4; ++i) {
        int m = m0 + ty * 4 + i;
        if (m < M) {
#pragma unroll
            for (int j = 0; j < 4; ++j) {
                int jj = j0 + tx * 4 + j;
                Cout[m * 1024 + jj] = acc[i][j] + b1[jj] + b2[jj];
            }
        }
    }
}

// ---------------------------------------------------------------------------
// Kernel 3: persistent forward-LSTM. 8 blocks x 256 threads.
// r9 = r6-proven producer protocol (relaxed h stores -> block barrier ->
//      single RELEASE flag per block: compiler emits vmcnt drain + L2
//      write-back so h reaches L3 BEFORE the flag)
//    + r8 consumer improvement (A-fragments loaded directly from hbuf into
//      MFMA registers via 16x dwordx4 sc0 sc1 -- no LDS stage, one fewer
//      barrier).
// ---------------------------------------------------------------------------
__global__ __launch_bounds__(256) void lstm_persist(
    const float* __restrict__ xg,     // [50][32][1024]
    const float* __restrict__ w_hh,   // [1024][256] row-major
    float*       __restrict__ last_f, // [32][256]
    unsigned long long* __restrict__ hbuf,   // [2][32][64] u64 (4xbf16)
    unsigned*    __restrict__ flags)  // [NB*FSTR], flag i at i*FSTR
{
    __shared__ __align__(16) __bf16 w_s[RWS * WPAD];   // 66 KB
    __shared__ __align__(16) float  g_s[Bb * GPAD];    // 16.5 KB
    __shared__ __align__(16) float  c_s[Bb * CPAD];    // 4.5 KB

    const int tid = threadIdx.x, blk = blockIdx.x;
    const int hs0 = blk * HS;

    for (int i = tid; i < RWS * Ee; i += 256) {
        int r = i >> 8, k = i & 255;
        int grow = (r >> 5) * Hh + hs0 + (r & 31);
        w_s[r * WPAD + k] = (__bf16)w_hh[grow * Hh + k];
    }
    for (int i = tid; i < Bb * CPAD; i += 256) c_s[i] = 0.f;
    __syncthreads();

    const int l  = tid & 63, wvi = tid >> 6;
    const int lr = l & 15,   lq  = l >> 4;
    const int b_nl = tid >> 3, jg = tid & 7;
    const int col = hs0 + jg * 4;

    // prefetch xg(0)
    const float* x0 = xg + (size_t)b_nl * 1024;
    f32x4 ngi = *(const f32x4*)&x0[0 * Hh + col];
    f32x4 ngf = *(const f32x4*)&x0[1 * Hh + col];
    f32x4 ngg = *(const f32x4*)&x0[2 * Hh + col];
    f32x4 ngo = *(const f32x4*)&x0[3 * Hh + col];

    for (int t = 0; t < Vv; ++t) {
        if (t > 0) {
            // ---- 8 pollers: one lane per producer flag (relaxed spin) ----
            if (tid < NB) {
                const unsigned* fa = flags + tid * FSTR;
                int guard = 0;
                while (__hip_atomic_load(fa, __ATOMIC_RELAXED,
                                         __HIP_MEMORY_SCOPE_AGENT) < (unsigned)t &&
                       ++guard < (1 << 22)) {
                    __builtin_amdgcn_s_sleep(1);
                }
            }
            __syncthreads();

            // ---- A-fragments direct from hbuf (coherent bypass loads) ----
            // lane (lr,lq), chunk kt: h[batch=lr][k=kt*32+lq*8 ..+8]
            f32x4 a0r[8], a1r[8];
            {
                const char* hb = (const char*)(hbuf + (t & 1) * (Bb * 64));
                const char* base0 = hb + (size_t)(lr * 512 + lq * 16);
                const char* base1 = base0 + 16 * 512;
                asm volatile(
                    "global_load_dwordx4 %0, %8, off sc0 sc1\n\t"
                    "global_load_dwordx4 %1, %8, off offset:64 sc0 sc1\n\t"
                    "global_load_dwordx4 %2, %8, off offset:128 sc0 sc1\n\t"
                    "global_load_dwordx4 %3, %8, off offset:192 sc0 sc1\n\t"
                    "global_load_dwordx4 %4, %8, off offset:256 sc0 sc1\n\t"
                    "global_load_dwordx4 %5, %8, off offset:320 sc0 sc1\n\t"
                    "global_load_dwordx4 %6, %8, off offset:384 sc0 sc1\n\t"
                    "global_load_dwordx4 %7, %8, off offset:448 sc0 sc1"
                    : "=&v"(a0r[0]), "=&v"(a0r[1]), "=&v"(a0r[2]), "=&v"(a0r[3]),
                      "=&v"(a0r[4]), "=&v"(a0r[5]), "=&v"(a0r[6]), "=&v"(a0r[7])
                    : "v"(base0) : "memory");
                asm volatile(
                    "global_load_dwordx4 %0, %8, off sc0 sc1\n\t"
                    "global_load_dwordx4 %1, %8, off offset:64 sc0 sc1\n\t"
                    "global_load_dwordx4 %2, %8, off offset:128 sc0 sc1\n\t"
                    "global_load_dwordx4 %3, %8, off offset:192 sc0 sc1\n\t"
                    "global_load_dwordx4 %4, %8, off offset:256 sc0 sc1\n\t"
                    "global_load_dwordx4 %5, %8, off offset:320 sc0 sc1\n\t"
                    "global_load_dwordx4 %6, %8, off offset:384 sc0 sc1\n\t"
                    "global_load_dwordx4 %7, %8, off offset:448 sc0 sc1\n\t"
                    "s_waitcnt vmcnt(0)"
                    : "=&v"(a1r[0]), "=&v"(a1r[1]), "=&v"(a1r[2]), "=&v"(a1r[3]),
                      "=&v"(a1r[4]), "=&v"(a1r[5]), "=&v"(a1r[6]), "=&v"(a1r[7])
                    : "v"(base1) : "memory");
                __builtin_amdgcn_sched_barrier(0);
            }

            // ---- G[32][128] = h[32][256] @ w_slice^T ----
            f32x4 a00 = {}, a01 = {}, a10 = {}, a11 = {};
#pragma unroll
            for (int kt = 0; kt < 8; ++kt) {
                int ko = kt * 32 + lq * 8;
                bf16x8 A0 = __builtin_bit_cast(bf16x8, a0r[kt]);
                bf16x8 A1 = __builtin_bit_cast(bf16x8, a1r[kt]);
                bf16x8 B0 = *(const bf16x8*)&w_s[(wvi * 32 + lr) * WPAD + ko];
                bf16x8 B1 = *(const bf16x8*)&w_s[(wvi * 32 + 16 + lr) * WPAD + ko];
                a00 = __builtin_amdgcn_mfma_f32_16x16x32_bf16(A0, B0, a00, 0, 0, 0);
                a01 = __builtin_amdgcn_mfma_f32_16x16x32_bf16(A0, B1, a01, 0, 0, 0);
                a10 = __builtin_amdgcn_mfma_f32_16x16x32_bf16(A1, B0, a10, 0, 0, 0);
                a11 = __builtin_amdgcn_mfma_f32_16x16x32_bf16(A1, B1, a11, 0, 0, 0);
            }
#pragma unroll
            for (int r = 0; r < 4; ++r) {
                int b0 = lq * 4 + r;
                g_s[b0 * GPAD + wvi * 32 + lr]             = a00[r];
                g_s[b0 * GPAD + wvi * 32 + 16 + lr]        = a01[r];
                g_s[(16 + b0) * GPAD + wvi * 32 + lr]      = a10[r];
                g_s[(16 + b0) * GPAD + wvi * 32 + 16 + lr] = a11[r];
            }
            __syncthreads();
        }

        // ---- nonlinearity (prefetched xg(t)); prefetch t+1; compute h ----
        {
            f32x4 gi = ngi, gf = ngf, gg = ngg, go = ngo;
            if (t + 1 < Vv) {
                const float* nx = xg + ((size_t)(t + 1) * Bb + b_nl) * 1024;
                ngi = *(const f32x4*)&nx[0 * Hh + col];
                ngf = *(const f32x4*)&nx[1 * Hh + col];
                ngg = *(const f32x4*)&nx[2 * Hh + col];
                ngo = *(const f32x4*)&nx[3 * Hh + col];
            }
            if (t > 0) {
                int gb = b_nl * GPAD + jg * 4;
                gi += *(const f32x4*)&g_s[gb + 0 * HS];
                gf += *(const f32x4*)&g_s[gb + 1 * HS];
                gg += *(const f32x4*)&g_s[gb + 2 * HS];
                go += *(const f32x4*)&g_s[gb + 3 * HS];
            }
            f32x4 cv = *(const f32x4*)&c_s[b_nl * CPAD + jg * 4];
            float hnew[4];
#pragma unroll
            for (int u = 0; u < 4; ++u) {
                float iv = sigmoidf_(gi[u]);
                float fv = sigmoidf_(gf[u]);
                float gv = tanhf_(gg[u]);
                float ov = sigmoidf_(go[u]);
                float cn = fv * cv[u] + iv * gv;
                cv[u] = cn;
                hnew[u] = ov * tanhf_(cn);
            }
            *(f32x4*)&c_s[b_nl * CPAD + jg * 4] = cv;

            if (t < Vv - 1) {
                unsigned u0 =
                    ((unsigned)__builtin_bit_cast(unsigned short, (__bf16)hnew[0])) |
                    ((unsigned)__builtin_bit_cast(unsigned short, (__bf16)hnew[1]) << 16);
                unsigned u1 =
                    ((unsigned)__builtin_bit_cast(unsigned short, (__bf16)hnew[2])) |
                    ((unsigned)__builtin_bit_cast(unsigned short, (__bf16)hnew[3]) << 16);
                unsigned long long hv = (unsigned long long)u0 |
                                        ((unsigned long long)u1 << 32);
                int base = b_nl * 64 + blk * 8 + jg;
                __hip_atomic_store(hbuf + ((t + 1) & 1) * (Bb * 64) + base, hv,
                                   __ATOMIC_RELAXED, __HIP_MEMORY_SCOPE_AGENT);
            } else {
                f32x4 hv = {hnew[0], hnew[1], hnew[2], hnew[3]};
                *(f32x4*)&last_f[b_nl * Hh + hs0 + jg * 4] = hv;
            }
        }

        if (t < Vv - 1) {
            // block barrier, then ONE RELEASE flag store (proper L3 push)
            __syncthreads();
            if (tid == 0) {
                __hip_atomic_store(&flags[blk * FSTR], (unsigned)(t + 1),
                                   __ATOMIC_RELEASE, __HIP_MEMORY_SCOPE_AGENT);
            }
        }
    }
}

// ---------------------------------------------------------------------------
// Kernel 4: tail — backward single cell + head + softmax.
// ---------------------------------------------------------------------------
__global__ __launch_bounds__(512) void lstm_tail(
    const float* __restrict__ last_f,
    const float* __restrict__ xgb,
    const float* __restrict__ W_out,
    const float* __restrict__ b_out,
    float*       __restrict__ out)
{
    __shared__ float last_s[2 * Hh];
    __shared__ float logits_s[Ll];
    const int b = blockIdx.x, tid = threadIdx.x;

    if (tid < Hh) {
        last_s[tid] = last_f[b * Hh + tid];
    } else {
        int j = tid - Hh;
        float ig = sigmoidf_(xgb[b * 1024 + j]);
        float gg = tanhf_(xgb[b * 1024 + 2 * Hh + j]);
        float og = sigmoidf_(xgb[b * 1024 + 3 * Hh + j]);
        last_s[Hh + j] = og * tanhf_(ig * gg);
    }
    __syncthreads();

    if (tid < Ll) {
        float acc = b_out[tid];
        for (int q = 0; q < 2 * Hh; ++q)
            acc = fmaf(last_s[q], W_out[tid * 2 * Hh + q], acc);
        logits_s[tid] = acc;
    }
    __syncthreads();
    if (tid == 0) {
        float mx = -3.0e38f;
        for (int i = 0; i < Ll; ++i) mx = fmaxf(mx, logits_s[i]);
        float ex[Ll], s = 0.f;
        for (int i = 0; i < Ll; ++i) { ex[i] = __expf(logits_s[i] - mx); s += ex[i]; }
        float inv = 1.0f / s;
        for (int i = 0; i < Ll; ++i) out[b * Ll + i] = ex[i] * inv;
    }
}

// ---------------------------------------------------------------------------
extern "C" void kernel_launch(void* const* d_in, const int* in_sizes, int n_in,
                              void* d_out, int out_size, void* d_ws, size_t ws_size,
                              hipStream_t stream) {
    const int*   codes     = (const int*)  d_in[0];
    const float* mask      = (const float*)d_in[1];
    const float* tvals     = (const float*)d_in[2];
    const float* emb_table = (const float*)d_in[4];
    const float* WQ1       = (const float*)d_in[5];
    const float* WK1       = (const float*)d_in[6];
    const float* decay     = (const float*)d_in[7];
    const float* initial   = (const float*)d_in[8];
    const float* w_ih_f    = (const float*)d_in[9];
    const float* w_hh_f    = (const float*)d_in[10];
    const float* b_ih_f    = (const float*)d_in[11];
    const float* b_hh_f    = (const float*)d_in[12];
    const float* w_ih_b    = (const float*)d_in[13];
    // d_in[14] = w_hh_b: unused (backward output = first scan step, h0=c0=0)
    const float* b_ih_b    = (const float*)d_in[15];
    const float* b_hh_b    = (const float*)d_in[16];
    const float* W_out     = (const float*)d_in[17];
    const float* b_out     = (const float*)d_in[18];
    float* out = (float*)d_out;

    // workspace layout
    float* ws      = (float*)d_ws;
    float* vv      = ws;                 // 409600 f
    float* xg_f    = vv + 409600;        // 1638400 f
    float* xgb     = xg_f + 1638400;     // 32768 f
    float* last_f  = xgb + 32768;        // 8192 f
    __bf16* wqhi   = (__bf16*)(last_f + 8192);
    __bf16* wqlo   = wqhi + 32768;
    __bf16* wkhi   = wqlo + 32768;
    __bf16* wklo   = wkhi + 32768;
    unsigned long long* hbuf = (unsigned long long*)(wklo + 32768); // 4096 u64
    unsigned* flags = (unsigned*)(hbuf + 4096);                     // NB*FSTR u32

    wsplit<<<256, 256, 0, stream>>>(WQ1, WK1, wqhi, wqlo, wkhi, wklo, flags);
    attn_v2<<<BVn, 256, 0, stream>>>(codes, mask, tvals, emb_table,
                                     wqhi, wqlo, wkhi, wklo,
                                     decay, initial, vv);
    xw_kernel<<<dim3(26, 16), 256, 0, stream>>>(vv, w_ih_f, b_ih_f, b_hh_f,
                                                w_ih_b, b_ih_b, b_hh_b,
                                                xg_f, xgb);
    lstm_persist<<<NB, 256, 0, stream>>>(xg_f, w_hh_f, last_f, hbuf, flags);
    lstm_tail<<<Bb, 512, 0, stream>>>(last_f, xgb, W_out, b_out, out);
}

// Round 10
// 304.739 us; speedup vs baseline: 1.2777x; 1.2777x over previous
//
#include <hip/hip_runtime.h>
#include <hip/hip_bf16.h>
#include <math.h>

// Problem constants (from reference)
#define Bb 32
#define Vv 50
#define Cc 64
#define Ee 256
#define Aa 128
#define Hh 256
#define Ll 10
#define BVn (Bb*Vv)          // 1600
#define SCALE 0.08838834764831845f   // 1/sqrt(128)

// persistent-LSTM config
#define NB 8          // blocks
#define HS 32         // hidden units per block
#define RWS (4*HS)    // gate rows per block = 128
#define WPAD 264      // bf16 row stride
#define GPAD 132      // f32 row stride for gates scratch
#define CPAD 36       // f32 row stride for c state
#define NREC 2048     // records per parity buffer (32 batch x 64)
#define RBUFB 32768   // bytes per parity buffer (NREC*16)

// attn LDS strides (bf16 elements)
#define EPAD 264
#define QPAD 136

typedef __bf16 bf16x8 __attribute__((ext_vector_type(8)));
typedef float  f32x4  __attribute__((ext_vector_type(4)));
typedef unsigned u32x4 __attribute__((ext_vector_type(4)));

__device__ __forceinline__ float sigmoidf_(float x) {
    return 1.0f / (1.0f + __expf(-x));
}
__device__ __forceinline__ float tanhf_(float x) {
    return 1.0f - 2.0f / (__expf(2.0f * x) + 1.0f);
}

// ---------------------------------------------------------------------------
// Kernel 0: decompose WQ1/WK1 into bf16 hi/lo pairs; blocks 0..15 zero the
// tagged h-record buffer (bypass stores -> visible to lstm's bypass reads).
// ---------------------------------------------------------------------------
__global__ __launch_bounds__(256) void wsplit(
    const float* __restrict__ wq, const float* __restrict__ wk,
    __bf16* __restrict__ qh, __bf16* __restrict__ ql,
    __bf16* __restrict__ kh, __bf16* __restrict__ kl,
    u32x4* __restrict__ hrec)
{
    if (blockIdx.x < 16) {
        int g = blockIdx.x * 256 + threadIdx.x;   // 0..4095 -> 64 KB
        u32x4 z = {0u, 0u, 0u, 0u};
        char* dst = (char*)hrec + (size_t)g * 16;
        asm volatile("global_store_dwordx4 %0, %1, off sc0 sc1"
                     :: "v"(dst), "v"(z) : "memory");
    }
    int i = blockIdx.x * 256 + threadIdx.x;    // 0..65535
    if (i < 32768) {
        float f = wq[i];
        __bf16 h = (__bf16)f;
        qh[i] = h; ql[i] = (__bf16)(f - (float)h);
    } else {
        int j = i - 32768;
        float f = wk[j];
        __bf16 h = (__bf16)f;
        kh[j] = h; kl[j] = (__bf16)(f - (float)h);
    }
}

// ---------------------------------------------------------------------------
// Kernel 1: attention — split-bf16 MFMA, in-register softmax. (unchanged)
// ---------------------------------------------------------------------------
__global__ __launch_bounds__(256, 2) void attn_v2(
    const int*   __restrict__ codes,
    const float* __restrict__ mask,
    const float* __restrict__ tvals,
    const float* __restrict__ emb_table,
    const __bf16* __restrict__ wqhi, const __bf16* __restrict__ wqlo,
    const __bf16* __restrict__ wkhi, const __bf16* __restrict__ wklo,
    const float* __restrict__ decay,
    const float* __restrict__ initial,
    float*       __restrict__ vv)
{
    __shared__ __align__(16) __bf16 buf[4 * Cc * QPAD];
    __shared__ int   codes_l[Cc];
    __shared__ float maskcol_s[Cc], coef_s[Cc], wsum_s[Cc];
    __shared__ float wpart[4][Cc];

    __bf16* ehi = buf;
    __bf16* elo = buf + Cc * EPAD;
    __bf16* qhi = buf;
    __bf16* qlo = buf + 1 * Cc * QPAD;
    __bf16* khi = buf + 2 * Cc * QPAD;
    __bf16* klo = buf + 3 * Cc * QPAD;

    const int n   = blockIdx.x;
    const int tid = threadIdx.x;
    const int b   = n / Vv;
    const int v   = n - b * Vv;
    const int wv  = tid >> 6;
    const int lane = tid & 63;
    const int lr  = lane & 15;
    const int lq  = lane >> 4;

    if (tid < Cc) {
        codes_l[tid]   = codes[n * Cc + tid];
        maskcol_s[tid] = mask[n * Cc + tid];
    }
    __syncthreads();

    for (int i = tid; i < Cc * Ee; i += 256) {
        int c = i >> 8, e = i & 255;
        float f = emb_table[(size_t)codes_l[c] * Ee + e];
        __bf16 h = (__bf16)f;
        ehi[c * EPAD + e] = h;
        elo[c * EPAD + e] = (__bf16)(f - (float)h);
    }
    if (tid < Cc) {
        int code = codes_l[tid];
        float keep = (maskcol_s[tid] == 0.0f) ? 1.0f : 0.0f;
        coef_s[tid] = keep * sigmoidf_(decay[code] * tvals[n] + initial[code]);
    }
    __syncthreads();

    const __bf16* bh = (wv < 2) ? wqhi : wkhi;
    const __bf16* bl = (wv < 2) ? wqlo : wklo;
    const int colbase = (wv & 1) * 64;

    f32x4 acc[4][4] = {};
    for (int kt = 0; kt < 8; ++kt) {
        const int k0 = kt * 32 + lq * 8;
        bf16x8 Ahh[4], All[4], Bhh[4], Bll[4];
#pragma unroll
        for (int mf = 0; mf < 4; ++mf) {
            Ahh[mf] = *(const bf16x8*)&ehi[(mf * 16 + lr) * EPAD + k0];
            All[mf] = *(const bf16x8*)&elo[(mf * 16 + lr) * EPAD + k0];
        }
#pragma unroll
        for (int nf = 0; nf < 4; ++nf) {
            const int row = colbase + nf * 16 + lr;
            Bhh[nf] = *(const bf16x8*)&bh[row * Ee + k0];
            Bll[nf] = *(const bf16x8*)&bl[row * Ee + k0];
        }
#pragma unroll
        for (int mf = 0; mf < 4; ++mf)
#pragma unroll
            for (int nf = 0; nf < 4; ++nf) {
                acc[mf][nf] = __builtin_amdgcn_mfma_f32_16x16x32_bf16(Ahh[mf], Bhh[nf], acc[mf][nf], 0, 0, 0);
                acc[mf][nf] = __builtin_amdgcn_mfma_f32_16x16x32_bf16(Ahh[mf], Bll[nf], acc[mf][nf], 0, 0, 0);
                acc[mf][nf] = __builtin_amdgcn_mfma_f32_16x16x32_bf16(All[mf], Bhh[nf], acc[mf][nf], 0, 0, 0);
            }
    }
    __syncthreads();

    {
        __bf16* dh = (wv < 2) ? qhi : khi;
        __bf16* dl = (wv < 2) ? qlo : klo;
#pragma unroll
        for (int mf = 0; mf < 4; ++mf)
#pragma unroll
            for (int nf = 0; nf < 4; ++nf) {
                const int colb = colbase + nf * 16 + lr;
#pragma unroll
                for (int r = 0; r < 4; ++r) {
                    const int m = mf * 16 + lq * 4 + r;
                    float q = acc[mf][nf][r];
                    __bf16 h = (__bf16)q;
                    dh[m * QPAD + colb] = h;
                    dl[m * QPAD + colb] = (__bf16)(q - (float)h);
                }
            }
    }
    __syncthreads();

    f32x4 dacc[4] = {};
    for (int kt = 0; kt < 4; ++kt) {
        const int k0 = kt * 32 + lq * 8;
        bf16x8 Ahh = *(const bf16x8*)&qhi[(wv * 16 + lr) * QPAD + k0];
        bf16x8 All = *(const bf16x8*)&qlo[(wv * 16 + lr) * QPAD + k0];
#pragma unroll
        for (int nf = 0; nf < 4; ++nf) {
            bf16x8 Bhh = *(const bf16x8*)&khi[(nf * 16 + lr) * QPAD + k0];
            bf16x8 Bll = *(const bf16x8*)&klo[(nf * 16 + lr) * QPAD + k0];
            dacc[nf] = __builtin_amdgcn_mfma_f32_16x16x32_bf16(Ahh, Bhh, dacc[nf], 0, 0, 0);
            dacc[nf] = __builtin_amdgcn_mfma_f32_16x16x32_bf16(Ahh, Bll, dacc[nf], 0, 0, 0);
            dacc[nf] = __builtin_amdgcn_mfma_f32_16x16x32_bf16(All, Bhh, dacc[nf], 0, 0, 0);
        }
    }

    float p[4][4], inv[4];
#pragma unroll
    for (int r = 0; r < 4; ++r) {
#pragma unroll
        for (int nf = 0; nf < 4; ++nf)
            p[r][nf] = (dacc[nf][r] - maskcol_s[nf * 16 + lr]) * SCALE;
        float mx = fmaxf(fmaxf(p[r][0], p[r][1]), fmaxf(p[r][2], p[r][3]));
        mx = fmaxf(mx, __shfl_xor(mx, 1));
        mx = fmaxf(mx, __shfl_xor(mx, 2));
        mx = fmaxf(mx, __shfl_xor(mx, 4));
        mx = fmaxf(mx, __shfl_xor(mx, 8));
        float s = 0.f;
#pragma unroll
        for (int nf = 0; nf < 4; ++nf) { p[r][nf] = __expf(p[r][nf] - mx); s += p[r][nf]; }
        s += __shfl_xor(s, 1);
        s += __shfl_xor(s, 2);
        s += __shfl_xor(s, 4);
        s += __shfl_xor(s, 8);
        inv[r] = 1.0f / s;
    }

    float part[4];
#pragma unroll
    for (int nf = 0; nf < 4; ++nf) {
        float a = 0.f;
#pragma unroll
        for (int r = 0; r < 4; ++r) {
            const int row = wv * 16 + lq * 4 + r;
            a = fmaf(coef_s[row] * inv[r], p[r][nf], a);
        }
        part[nf] = a;
    }
#pragma unroll
    for (int nf = 0; nf < 4; ++nf) {
        part[nf] += __shfl_xor(part[nf], 16);
        part[nf] += __shfl_xor(part[nf], 32);
    }
    if (lq == 0)
#pragma unroll
        for (int nf = 0; nf < 4; ++nf) wpart[wv][nf * 16 + lr] = part[nf];
    __syncthreads();
    if (tid < Cc)
        wsum_s[tid] = wpart[0][tid] + wpart[1][tid] + wpart[2][tid] + wpart[3][tid];
    __syncthreads();

    float a3 = 0.f;
#pragma unroll 8
    for (int d = 0; d < Cc; ++d)
        a3 = fmaf(wsum_s[d], emb_table[(size_t)codes_l[d] * Ee + tid], a3);
    vv[(v * Bb + b) * Ee + tid] = a3;
}

// ---------------------------------------------------------------------------
// Kernel 2: merged fwd+bwd x@W^T. blockIdx.x<25 -> forward; ==25 -> backward.
// ---------------------------------------------------------------------------
__global__ __launch_bounds__(256) void xw_kernel(
    const float* __restrict__ vv,
    const float* __restrict__ w_ih_f, const float* __restrict__ b_ih_f,
    const float* __restrict__ b_hh_f,
    const float* __restrict__ w_ih_b, const float* __restrict__ b_ih_b,
    const float* __restrict__ b_hh_b,
    float* __restrict__ xg_f, float* __restrict__ xgb)
{
    const bool bwd = (blockIdx.x == 25);
    const float* A  = bwd ? (vv + 49 * Bb * Ee) : vv;
    const float* W  = bwd ? w_ih_b : w_ih_f;
    const float* b1 = bwd ? b_ih_b : b_ih_f;
    const float* b2 = bwd ? b_hh_b : b_hh_f;
    float* Cout     = bwd ? xgb : xg_f;
    const int M     = bwd ? Bb : BVn;
    const int m0    = bwd ? 0 : blockIdx.x * 64;
    const int j0    = blockIdx.y * 64;

    __shared__ float a_s[64 * 65];
    __shared__ float w_s[64 * 65];
    const int tid = threadIdx.x, tx = tid & 15, ty = tid >> 4;
    float acc[4][4] = {};
    for (int kc = 0; kc < 256; kc += 64) {
        __syncthreads();
        for (int idx = tid; idx < 4096; idx += 256) {
            int r = idx >> 6, kk = idx & 63;
            int m = m0 + r;
            a_s[r * 65 + kk] = (m < M) ? A[m * 256 + kc + kk] : 0.f;
            w_s[r * 65 + kk] = W[(j0 + r) * 256 + kc + kk];
        }
        __syncthreads();
#pragma unroll 8
        for (int kk = 0; kk < 64; ++kk) {
            float av[4], wv[4];
#pragma unroll
            for (int i = 0; i < 4; ++i) av[i] = a_s[(ty * 4 + i) * 65 + kk];
#pragma unroll
            for (int j = 0; j < 4; ++j) wv[j] = w_s[(tx * 4 + j) * 65 + kk];
#pragma unroll
            for (int i = 0; i < 4; ++i)
#pragma unroll
                for (int j = 0; j < 4; ++j)
                    acc[i][j] = fmaf(av[i], wv[j], acc[i][j]);
        }
    }
#pragma unroll
    for (int i = 0; i < 4; ++i) {
        int m = m0 + ty * 4 + i;
        if (m < M) {
#pragma unroll
            for (int j = 0; j < 4; ++j) {
                int jj = j0 + tx * 4 + j;
                Cout[m * 1024 + jj] = acc[i][j] + b1[jj] + b2[jj];
            }
        }
    }
}

// ---------------------------------------------------------------------------
// Kernel 3: persistent forward-LSTM. 8 blocks x 256 threads.
// r10: TAGGED-RECORD sync. Producer thread stores one 16B record
// {tag, h01, h23, tag} with a single bypass dwordx4 store -- tag and data
// are inseparable, so NO drain / release / flags / producer barrier.
// Consumer poll IS the load: 256 threads poll-load 8 coalesced records each
// until both sandwich tags == t, stage payload to LDS (r6 layout), barrier,
// MFMA. Two barriers per step total.
// ---------------------------------------------------------------------------
__global__ __launch_bounds__(256) void lstm_persist(
    const float* __restrict__ xg,     // [50][32][1024]
    const float* __restrict__ w_hh,   // [1024][256] row-major
    float*       __restrict__ last_f, // [32][256]
    u32x4*       __restrict__ hrec)   // [2][NREC] tagged records
{
    __shared__ __align__(16) __bf16 w_s[RWS * WPAD];   // 66 KB
    __shared__ __align__(16) __bf16 h_s[Bb * WPAD];    // 16.5 KB
    __shared__ __align__(16) float  g_s[Bb * GPAD];    // 16.5 KB
    __shared__ __align__(16) float  c_s[Bb * CPAD];    // 4.5 KB

    const int tid = threadIdx.x, blk = blockIdx.x;
    const int hs0 = blk * HS;

    for (int i = tid; i < RWS * Ee; i += 256) {
        int r = i >> 8, k = i & 255;
        int grow = (r >> 5) * Hh + hs0 + (r & 31);
        w_s[r * WPAD + k] = (__bf16)w_hh[grow * Hh + k];
    }
    for (int i = tid; i < Bb * CPAD; i += 256) c_s[i] = 0.f;
    __syncthreads();

    const int l  = tid & 63, wvi = tid >> 6;
    const int lr = l & 15,   lq  = l >> 4;
    const int b_nl = tid >> 3, jg = tid & 7;
    const int col = hs0 + jg * 4;

    // prefetch xg(0)
    const float* x0 = xg + (size_t)b_nl * 1024;
    f32x4 ngi = *(const f32x4*)&x0[0 * Hh + col];
    f32x4 ngf = *(const f32x4*)&x0[1 * Hh + col];
    f32x4 ngg = *(const f32x4*)&x0[2 * Hh + col];
    f32x4 ngo = *(const f32x4*)&x0[3 * Hh + col];

    for (int t = 0; t < Vv; ++t) {
        if (t > 0) {
            // ---- poll-is-load: 8 coalesced records per thread ----
            const char* hb = (const char*)hrec + (size_t)(t & 1) * RBUFB;
            const char* a0 = hb + (size_t)tid * 16;
            const char* a1 = a0 + 1 * 4096;
            const char* a2 = a0 + 2 * 4096;
            const char* a3 = a0 + 3 * 4096;
            const char* a4 = a0 + 4 * 4096;
            const char* a5 = a0 + 5 * 4096;
            const char* a6 = a0 + 6 * 4096;
            const char* a7 = a0 + 7 * 4096;
            u32x4 rc[8];
            const unsigned tt = (unsigned)t;
            int guard = 0;
            bool ok;
            do {
                asm volatile(
                    "global_load_dwordx4 %0, %8, off sc0 sc1\n\t"
                    "global_load_dwordx4 %1, %9, off sc0 sc1\n\t"
                    "global_load_dwordx4 %2, %10, off sc0 sc1\n\t"
                    "global_load_dwordx4 %3, %11, off sc0 sc1\n\t"
                    "global_load_dwordx4 %4, %12, off sc0 sc1\n\t"
                    "global_load_dwordx4 %5, %13, off sc0 sc1\n\t"
                    "global_load_dwordx4 %6, %14, off sc0 sc1\n\t"
                    "global_load_dwordx4 %7, %15, off sc0 sc1\n\t"
                    "s_waitcnt vmcnt(0)"
                    : "=&v"(rc[0]), "=&v"(rc[1]), "=&v"(rc[2]), "=&v"(rc[3]),
                      "=&v"(rc[4]), "=&v"(rc[5]), "=&v"(rc[6]), "=&v"(rc[7])
                    : "v"(a0), "v"(a1), "v"(a2), "v"(a3),
                      "v"(a4), "v"(a5), "v"(a6), "v"(a7)
                    : "memory");
                ok = true;
#pragma unroll
                for (int q = 0; q < 8; ++q)
                    ok = ok & (rc[q][0] == tt) & (rc[q][3] == tt);
            } while (!ok && ++guard < (1 << 16));

            // ---- stage payloads to LDS (r6 layout) ----
#pragma unroll
            for (int q = 0; q < 8; ++q) {
                int rec = tid + 256 * q;
                unsigned long long pay =
                    ((unsigned long long)rc[q][2] << 32) | rc[q][1];
                *(unsigned long long*)&h_s[(rec >> 6) * WPAD + (rec & 63) * 4] = pay;
            }
            __syncthreads();   // BARRIER A: h_s ready; also fences g_s reuse

            // ---- G[32][128] = h[32][256] @ w_slice^T ----
            f32x4 a00 = {}, a01 = {}, a10 = {}, a11 = {};
#pragma unroll
            for (int kt = 0; kt < 8; ++kt) {
                int ko = kt * 32 + lq * 8;
                bf16x8 A0 = *(const bf16x8*)&h_s[lr * WPAD + ko];
                bf16x8 A1 = *(const bf16x8*)&h_s[(16 + lr) * WPAD + ko];
                bf16x8 B0 = *(const bf16x8*)&w_s[(wvi * 32 + lr) * WPAD + ko];
                bf16x8 B1 = *(const bf16x8*)&w_s[(wvi * 32 + 16 + lr) * WPAD + ko];
                a00 = __builtin_amdgcn_mfma_f32_16x16x32_bf16(A0, B0, a00, 0, 0, 0);
                a01 = __builtin_amdgcn_mfma_f32_16x16x32_bf16(A0, B1, a01, 0, 0, 0);
                a10 = __builtin_amdgcn_mfma_f32_16x16x32_bf16(A1, B0, a10, 0, 0, 0);
                a11 = __builtin_amdgcn_mfma_f32_16x16x32_bf16(A1, B1, a11, 0, 0, 0);
            }
#pragma unroll
            for (int r = 0; r < 4; ++r) {
                int b0 = lq * 4 + r;
                g_s[b0 * GPAD + wvi * 32 + lr]             = a00[r];
                g_s[b0 * GPAD + wvi * 32 + 16 + lr]        = a01[r];
                g_s[(16 + b0) * GPAD + wvi * 32 + lr]      = a10[r];
                g_s[(16 + b0) * GPAD + wvi * 32 + 16 + lr] = a11[r];
            }
            __syncthreads();   // BARRIER B: g_s ready
        }

        // ---- nonlinearity (prefetched xg(t)); prefetch t+1; publish ----
        {
            f32x4 gi = ngi, gf = ngf, gg = ngg, go = ngo;
            if (t + 1 < Vv) {
                const float* nx = xg + ((size_t)(t + 1) * Bb + b_nl) * 1024;
                ngi = *(const f32x4*)&nx[0 * Hh + col];
                ngf = *(const f32x4*)&nx[1 * Hh + col];
                ngg = *(const f32x4*)&nx[2 * Hh + col];
                ngo = *(const f32x4*)&nx[3 * Hh + col];
            }
            if (t > 0) {
                int gb = b_nl * GPAD + jg * 4;
                gi += *(const f32x4*)&g_s[gb + 0 * HS];
                gf += *(const f32x4*)&g_s[gb + 1 * HS];
                gg += *(const f32x4*)&g_s[gb + 2 * HS];
                go += *(const f32x4*)&g_s[gb + 3 * HS];
            }
            f32x4 cv = *(const f32x4*)&c_s[b_nl * CPAD + jg * 4];
            float hnew[4];
#pragma unroll
            for (int u = 0; u < 4; ++u) {
                float iv = sigmoidf_(gi[u]);
                float fv = sigmoidf_(gf[u]);
                float gv = tanhf_(gg[u]);
                float ov = sigmoidf_(go[u]);
                float cn = fv * cv[u] + iv * gv;
                cv[u] = cn;
                hnew[u] = ov * tanhf_(cn);
            }
            *(f32x4*)&c_s[b_nl * CPAD + jg * 4] = cv;

            if (t < Vv - 1) {
                unsigned u0 =
                    ((unsigned)__builtin_bit_cast(unsigned short, (__bf16)hnew[0])) |
                    ((unsigned)__builtin_bit_cast(unsigned short, (__bf16)hnew[1]) << 16);
                unsigned u1 =
                    ((unsigned)__builtin_bit_cast(unsigned short, (__bf16)hnew[2])) |
                    ((unsigned)__builtin_bit_cast(unsigned short, (__bf16)hnew[3]) << 16);
                const unsigned tt1 = (unsigned)(t + 1);
                u32x4 outrec;
                outrec[0] = tt1; outrec[1] = u0; outrec[2] = u1; outrec[3] = tt1;
                char* dst = (char*)hrec + (size_t)((t + 1) & 1) * RBUFB
                          + (size_t)(b_nl * 64 + blk * 8 + jg) * 16;
                asm volatile("global_store_dwordx4 %0, %1, off sc0 sc1"
                             :: "v"(dst), "v"(outrec) : "memory");
            } else {
                f32x4 hv = {hnew[0], hnew[1], hnew[2], hnew[3]};
                *(f32x4*)&last_f[b_nl * Hh + hs0 + jg * 4] = hv;
            }
        }
        // no end-of-iteration barrier: the next poll gates progress
    }
}

// ---------------------------------------------------------------------------
// Kernel 4: tail — backward single cell + head + softmax.
// ---------------------------------------------------------------------------
__global__ __launch_bounds__(512) void lstm_tail(
    const float* __restrict__ last_f,
    const float* __restrict__ xgb,
    const float* __restrict__ W_out,
    const float* __restrict__ b_out,
    float*       __restrict__ out)
{
    __shared__ float last_s[2 * Hh];
    __shared__ float logits_s[Ll];
    const int b = blockIdx.x, tid = threadIdx.x;

    if (tid < Hh) {
        last_s[tid] = last_f[b * Hh + tid];
    } else {
        int j = tid - Hh;
        float ig = sigmoidf_(xgb[b * 1024 + j]);
        float gg = tanhf_(xgb[b * 1024 + 2 * Hh + j]);
        float og = sigmoidf_(xgb[b * 1024 + 3 * Hh + j]);
        last_s[Hh + j] = og * tanhf_(ig * gg);
    }
    __syncthreads();

    if (tid < Ll) {
        float acc = b_out[tid];
        for (int q = 0; q < 2 * Hh; ++q)
            acc = fmaf(last_s[q], W_out[tid * 2 * Hh + q], acc);
        logits_s[tid] = acc;
    }
    __syncthreads();
    if (tid == 0) {
        float mx = -3.0e38f;
        for (int i = 0; i < Ll; ++i) mx = fmaxf(mx, logits_s[i]);
        float ex[Ll], s = 0.f;
        for (int i = 0; i < Ll; ++i) { ex[i] = __expf(logits_s[i] - mx); s += ex[i]; }
        float inv = 1.0f / s;
        for (int i = 0; i < Ll; ++i) out[b * Ll + i] = ex[i] * inv;
    }
}

// ---------------------------------------------------------------------------
extern "C" void kernel_launch(void* const* d_in, const int* in_sizes, int n_in,
                              void* d_out, int out_size, void* d_ws, size_t ws_size,
                              hipStream_t stream) {
    const int*   codes     = (const int*)  d_in[0];
    const float* mask      = (const float*)d_in[1];
    const float* tvals     = (const float*)d_in[2];
    const float* emb_table = (const float*)d_in[4];
    const float* WQ1       = (const float*)d_in[5];
    const float* WK1       = (const float*)d_in[6];
    const float* decay     = (const float*)d_in[7];
    const float* initial   = (const float*)d_in[8];
    const float* w_ih_f    = (const float*)d_in[9];
    const float* w_hh_f    = (const float*)d_in[10];
    const float* b_ih_f    = (const float*)d_in[11];
    const float* b_hh_f    = (const float*)d_in[12];
    const float* w_ih_b    = (const float*)d_in[13];
    // d_in[14] = w_hh_b: unused (backward output = first scan step, h0=c0=0)
    const float* b_ih_b    = (const float*)d_in[15];
    const float* b_hh_b    = (const float*)d_in[16];
    const float* W_out     = (const float*)d_in[17];
    const float* b_out     = (const float*)d_in[18];
    float* out = (float*)d_out;

    // workspace layout
    float* ws      = (float*)d_ws;
    float* vv      = ws;                 // 409600 f
    float* xg_f    = vv + 409600;        // 1638400 f
    float* xgb     = xg_f + 1638400;     // 32768 f
    float* last_f  = xgb + 32768;        // 8192 f
    __bf16* wqhi   = (__bf16*)(last_f + 8192);
    __bf16* wqlo   = wqhi + 32768;
    __bf16* wkhi   = wqlo + 32768;
    __bf16* wklo   = wkhi + 32768;
    u32x4* hrec    = (u32x4*)(wklo + 32768);   // 2*NREC records = 64 KB
    // total ~8.7 MB

    wsplit<<<256, 256, 0, stream>>>(WQ1, WK1, wqhi, wqlo, wkhi, wklo, hrec);
    attn_v2<<<BVn, 256, 0, stream>>>(codes, mask, tvals, emb_table,
                                     wqhi, wqlo, wkhi, wklo,
                                     decay, initial, vv);
    xw_kernel<<<dim3(26, 16), 256, 0, stream>>>(vv, w_ih_f, b_ih_f, b_hh_f,
                                                w_ih_b, b_ih_b, b_hh_b,
                                                xg_f, xgb);
    lstm_persist<<<NB, 256, 0, stream>>>(xg_f, w_hh_f, last_f, hrec);
    lstm_tail<<<Bb, 512, 0, stream>>>(last_f, xgb, W_out, b_out, out);
}

// Round 11
// 272.512 us; speedup vs baseline: 1.4288x; 1.1183x over previous
//
#include <hip/hip_runtime.h>
#include <hip/hip_bf16.h>
#include <math.h>

// Problem constants (from reference)
#define Bb 32
#define Vv 50
#define Cc 64
#define Ee 256
#define Aa 128
#define Hh 256
#define Ll 10
#define BVn (Bb*Vv)          // 1600
#define SCALE 0.08838834764831845f   // 1/sqrt(128)

// persistent-LSTM config
#define NB 8          // blocks
#define HS 32         // hidden units per block
#define RWS (4*HS)    // gate rows per block = 128
#define WPAD 264      // bf16 row stride
#define GPAD 132      // f32 row stride for gates scratch
#define CPAD 36       // f32 row stride for c state
#define NREC 2048     // records per parity buffer (32 batch x 64)
#define RBUFB 32768   // bytes per parity buffer (NREC*16)

// attn LDS strides (bf16 elements)
#define EPAD 264
#define QPAD 136

typedef __bf16 bf16x8 __attribute__((ext_vector_type(8)));
typedef float  f32x4  __attribute__((ext_vector_type(4)));
typedef unsigned u32x4 __attribute__((ext_vector_type(4)));

__device__ __forceinline__ float sigmoidf_(float x) {
    return 1.0f / (1.0f + __expf(-x));
}
__device__ __forceinline__ float tanhf_(float x) {
    return 1.0f - 2.0f / (__expf(2.0f * x) + 1.0f);
}

// split 8 consecutive f32 at p into bf16 hi/lo fragments
__device__ __forceinline__ void split8(const float* __restrict__ p,
                                       bf16x8& hi, bf16x8& lo) {
    f32x4 a = *(const f32x4*)p;
    f32x4 b = *(const f32x4*)(p + 4);
#pragma unroll
    for (int u = 0; u < 4; ++u) {
        __bf16 h0 = (__bf16)a[u];
        hi[u] = h0; lo[u] = (__bf16)(a[u] - (float)h0);
        __bf16 h1 = (__bf16)b[u];
        hi[4 + u] = h1; lo[4 + u] = (__bf16)(b[u] - (float)h1);
    }
}

// ---------------------------------------------------------------------------
// Kernel 0: decompose WQ1/WK1 into bf16 hi/lo pairs; blocks 0..15 zero the
// tagged h-record buffer (bypass stores -> visible to lstm's bypass reads).
// ---------------------------------------------------------------------------
__global__ __launch_bounds__(256) void wsplit(
    const float* __restrict__ wq, const float* __restrict__ wk,
    __bf16* __restrict__ qh, __bf16* __restrict__ ql,
    __bf16* __restrict__ kh, __bf16* __restrict__ kl,
    u32x4* __restrict__ hrec)
{
    if (blockIdx.x < 16) {
        int g = blockIdx.x * 256 + threadIdx.x;   // 0..4095 -> 64 KB
        u32x4 z = {0u, 0u, 0u, 0u};
        char* dst = (char*)hrec + (size_t)g * 16;
        asm volatile("global_store_dwordx4 %0, %1, off sc0 sc1"
                     :: "v"(dst), "v"(z) : "memory");
    }
    int i = blockIdx.x * 256 + threadIdx.x;    // 0..65535
    if (i < 32768) {
        float f = wq[i];
        __bf16 h = (__bf16)f;
        qh[i] = h; ql[i] = (__bf16)(f - (float)h);
    } else {
        int j = i - 32768;
        float f = wk[j];
        __bf16 h = (__bf16)f;
        kh[j] = h; kl[j] = (__bf16)(f - (float)h);
    }
}

// ---------------------------------------------------------------------------
// Kernel 1: attention — split-bf16 MFMA, in-register softmax.
// r11: float4-vectorized emb gather (packed u64 hi/lo LDS stores);
//      phase-1 kt loop unrolled x2 for load/MFMA pipelining.
// ---------------------------------------------------------------------------
__global__ __launch_bounds__(256, 2) void attn_v2(
    const int*   __restrict__ codes,
    const float* __restrict__ mask,
    const float* __restrict__ tvals,
    const float* __restrict__ emb_table,
    const __bf16* __restrict__ wqhi, const __bf16* __restrict__ wqlo,
    const __bf16* __restrict__ wkhi, const __bf16* __restrict__ wklo,
    const float* __restrict__ decay,
    const float* __restrict__ initial,
    float*       __restrict__ vv)
{
    __shared__ __align__(16) __bf16 buf[4 * Cc * QPAD];
    __shared__ int   codes_l[Cc];
    __shared__ float maskcol_s[Cc], coef_s[Cc], wsum_s[Cc];
    __shared__ float wpart[4][Cc];

    __bf16* ehi = buf;
    __bf16* elo = buf + Cc * EPAD;
    __bf16* qhi = buf;
    __bf16* qlo = buf + 1 * Cc * QPAD;
    __bf16* khi = buf + 2 * Cc * QPAD;
    __bf16* klo = buf + 3 * Cc * QPAD;

    const int n   = blockIdx.x;
    const int tid = threadIdx.x;
    const int b   = n / Vv;
    const int v   = n - b * Vv;
    const int wv  = tid >> 6;
    const int lane = tid & 63;
    const int lr  = lane & 15;
    const int lq  = lane >> 4;

    if (tid < Cc) {
        codes_l[tid]   = codes[n * Cc + tid];
        maskcol_s[tid] = mask[n * Cc + tid];
    }
    __syncthreads();

    // vectorized gather: 4096 float4s, pack 4 hi / 4 lo into u64 stores
    for (int i = tid; i < Cc * 64; i += 256) {
        int c = i >> 6, e4 = i & 63;
        f32x4 f = *(const f32x4*)&emb_table[(size_t)codes_l[c] * Ee + e4 * 4];
        unsigned short hh[4], ll[4];
#pragma unroll
        for (int u = 0; u < 4; ++u) {
            __bf16 h = (__bf16)f[u];
            hh[u] = __builtin_bit_cast(unsigned short, h);
            ll[u] = __builtin_bit_cast(unsigned short,
                                       (__bf16)(f[u] - (float)h));
        }
        unsigned long long hp =
            (unsigned long long)hh[0] | ((unsigned long long)hh[1] << 16) |
            ((unsigned long long)hh[2] << 32) | ((unsigned long long)hh[3] << 48);
        unsigned long long lp =
            (unsigned long long)ll[0] | ((unsigned long long)ll[1] << 16) |
            ((unsigned long long)ll[2] << 32) | ((unsigned long long)ll[3] << 48);
        *(unsigned long long*)&ehi[c * EPAD + e4 * 4] = hp;
        *(unsigned long long*)&elo[c * EPAD + e4 * 4] = lp;
    }
    if (tid < Cc) {
        int code = codes_l[tid];
        float keep = (maskcol_s[tid] == 0.0f) ? 1.0f : 0.0f;
        coef_s[tid] = keep * sigmoidf_(decay[code] * tvals[n] + initial[code]);
    }
    __syncthreads();

    const __bf16* bh = (wv < 2) ? wqhi : wkhi;
    const __bf16* bl = (wv < 2) ? wqlo : wklo;
    const int colbase = (wv & 1) * 64;

    f32x4 acc[4][4] = {};
#pragma unroll 2
    for (int kt = 0; kt < 8; ++kt) {
        const int k0 = kt * 32 + lq * 8;
        bf16x8 Ahh[4], All[4], Bhh[4], Bll[4];
#pragma unroll
        for (int mf = 0; mf < 4; ++mf) {
            Ahh[mf] = *(const bf16x8*)&ehi[(mf * 16 + lr) * EPAD + k0];
            All[mf] = *(const bf16x8*)&elo[(mf * 16 + lr) * EPAD + k0];
        }
#pragma unroll
        for (int nf = 0; nf < 4; ++nf) {
            const int row = colbase + nf * 16 + lr;
            Bhh[nf] = *(const bf16x8*)&bh[row * Ee + k0];
            Bll[nf] = *(const bf16x8*)&bl[row * Ee + k0];
        }
#pragma unroll
        for (int mf = 0; mf < 4; ++mf)
#pragma unroll
            for (int nf = 0; nf < 4; ++nf) {
                acc[mf][nf] = __builtin_amdgcn_mfma_f32_16x16x32_bf16(Ahh[mf], Bhh[nf], acc[mf][nf], 0, 0, 0);
                acc[mf][nf] = __builtin_amdgcn_mfma_f32_16x16x32_bf16(Ahh[mf], Bll[nf], acc[mf][nf], 0, 0, 0);
                acc[mf][nf] = __builtin_amdgcn_mfma_f32_16x16x32_bf16(All[mf], Bhh[nf], acc[mf][nf], 0, 0, 0);
            }
    }
    __syncthreads();

    {
        __bf16* dh = (wv < 2) ? qhi : khi;
        __bf16* dl = (wv < 2) ? qlo : klo;
#pragma unroll
        for (int mf = 0; mf < 4; ++mf)
#pragma unroll
            for (int nf = 0; nf < 4; ++nf) {
                const int colb = colbase + nf * 16 + lr;
#pragma unroll
                for (int r = 0; r < 4; ++r) {
                    const int m = mf * 16 + lq * 4 + r;
                    float q = acc[mf][nf][r];
                    __bf16 h = (__bf16)q;
                    dh[m * QPAD + colb] = h;
                    dl[m * QPAD + colb] = (__bf16)(q - (float)h);
                }
            }
    }
    __syncthreads();

    f32x4 dacc[4] = {};
#pragma unroll
    for (int kt = 0; kt < 4; ++kt) {
        const int k0 = kt * 32 + lq * 8;
        bf16x8 Ahh = *(const bf16x8*)&qhi[(wv * 16 + lr) * QPAD + k0];
        bf16x8 All = *(const bf16x8*)&qlo[(wv * 16 + lr) * QPAD + k0];
#pragma unroll
        for (int nf = 0; nf < 4; ++nf) {
            bf16x8 Bhh = *(const bf16x8*)&khi[(nf * 16 + lr) * QPAD + k0];
            bf16x8 Bll = *(const bf16x8*)&klo[(nf * 16 + lr) * QPAD + k0];
            dacc[nf] = __builtin_amdgcn_mfma_f32_16x16x32_bf16(Ahh, Bhh, dacc[nf], 0, 0, 0);
            dacc[nf] = __builtin_amdgcn_mfma_f32_16x16x32_bf16(Ahh, Bll, dacc[nf], 0, 0, 0);
            dacc[nf] = __builtin_amdgcn_mfma_f32_16x16x32_bf16(All, Bhh, dacc[nf], 0, 0, 0);
        }
    }

    float p[4][4], inv[4];
#pragma unroll
    for (int r = 0; r < 4; ++r) {
#pragma unroll
        for (int nf = 0; nf < 4; ++nf)
            p[r][nf] = (dacc[nf][r] - maskcol_s[nf * 16 + lr]) * SCALE;
        float mx = fmaxf(fmaxf(p[r][0], p[r][1]), fmaxf(p[r][2], p[r][3]));
        mx = fmaxf(mx, __shfl_xor(mx, 1));
        mx = fmaxf(mx, __shfl_xor(mx, 2));
        mx = fmaxf(mx, __shfl_xor(mx, 4));
        mx = fmaxf(mx, __shfl_xor(mx, 8));
        float s = 0.f;
#pragma unroll
        for (int nf = 0; nf < 4; ++nf) { p[r][nf] = __expf(p[r][nf] - mx); s += p[r][nf]; }
        s += __shfl_xor(s, 1);
        s += __shfl_xor(s, 2);
        s += __shfl_xor(s, 4);
        s += __shfl_xor(s, 8);
        inv[r] = 1.0f / s;
    }

    float part[4];
#pragma unroll
    for (int nf = 0; nf < 4; ++nf) {
        float a = 0.f;
#pragma unroll
        for (int r = 0; r < 4; ++r) {
            const int row = wv * 16 + lq * 4 + r;
            a = fmaf(coef_s[row] * inv[r], p[r][nf], a);
        }
        part[nf] = a;
    }
#pragma unroll
    for (int nf = 0; nf < 4; ++nf) {
        part[nf] += __shfl_xor(part[nf], 16);
        part[nf] += __shfl_xor(part[nf], 32);
    }
    if (lq == 0)
#pragma unroll
        for (int nf = 0; nf < 4; ++nf) wpart[wv][nf * 16 + lr] = part[nf];
    __syncthreads();
    if (tid < Cc)
        wsum_s[tid] = wpart[0][tid] + wpart[1][tid] + wpart[2][tid] + wpart[3][tid];
    __syncthreads();

    float a3 = 0.f;
#pragma unroll 8
    for (int d = 0; d < Cc; ++d)
        a3 = fmaf(wsum_s[d], emb_table[(size_t)codes_l[d] * Ee + tid], a3);
    vv[(v * Bb + b) * Ee + tid] = a3;
}

// ---------------------------------------------------------------------------
// Kernel 2 (r11): split-bf16 MFMA x@W^T, operands straight from global/L2.
// Grid (26, 8): bx<25 fwd 64-row tiles of vv; bx==25 bwd (last visit, M=32).
// by = 128-col tile. 4 waves: wave wvi owns cols wvi*32..+32 (2x16 frags).
// Fragment mapping copied from attn phase 1 (verified): A row = mf*16+lr,
// k = kt*32+lq*8; D row = lq*4+r, D col = lr.
// ---------------------------------------------------------------------------
__global__ __launch_bounds__(256) void xw_mfma(
    const float* __restrict__ vv,
    const float* __restrict__ w_ih_f, const float* __restrict__ b_ih_f,
    const float* __restrict__ b_hh_f,
    const float* __restrict__ w_ih_b, const float* __restrict__ b_ih_b,
    const float* __restrict__ b_hh_b,
    float* __restrict__ xg_f, float* __restrict__ xgb)
{
    const bool bwd = (blockIdx.x == 25);
    const float* A  = bwd ? (vv + 49 * Bb * Ee) : vv;
    const float* W  = bwd ? w_ih_b : w_ih_f;
    const float* b1 = bwd ? b_ih_b : b_ih_f;
    const float* b2 = bwd ? b_hh_b : b_hh_f;
    float* Cout     = bwd ? xgb : xg_f;
    const int M     = bwd ? Bb : BVn;
    const int m0    = bwd ? 0 : blockIdx.x * 64;
    const int j0    = blockIdx.y * 128;

    const int tid = threadIdx.x;
    const int wvi = tid >> 6;
    const int lane = tid & 63;
    const int lr = lane & 15, lq = lane >> 4;

    f32x4 acc[4][2] = {};
#pragma unroll 2
    for (int kt = 0; kt < 8; ++kt) {
        const int k0 = kt * 32 + lq * 8;
        bf16x8 Ahh[4], All[4], Bhh[2], Bll[2];
#pragma unroll
        for (int mf = 0; mf < 4; ++mf) {
            int arow = m0 + mf * 16 + lr;
            if (arow >= M) arow = M - 1;            // clamp (bwd tile)
            split8(A + (size_t)arow * Ee + k0, Ahh[mf], All[mf]);
        }
#pragma unroll
        for (int nf = 0; nf < 2; ++nf) {
            const int brow = j0 + wvi * 32 + nf * 16 + lr;
            split8(W + (size_t)brow * Ee + k0, Bhh[nf], Bll[nf]);
        }
#pragma unroll
        for (int mf = 0; mf < 4; ++mf)
#pragma unroll
            for (int nf = 0; nf < 2; ++nf) {
                acc[mf][nf] = __builtin_amdgcn_mfma_f32_16x16x32_bf16(Ahh[mf], Bhh[nf], acc[mf][nf], 0, 0, 0);
                acc[mf][nf] = __builtin_amdgcn_mfma_f32_16x16x32_bf16(Ahh[mf], Bll[nf], acc[mf][nf], 0, 0, 0);
                acc[mf][nf] = __builtin_amdgcn_mfma_f32_16x16x32_bf16(All[mf], Bhh[nf], acc[mf][nf], 0, 0, 0);
            }
    }

#pragma unroll
    for (int mf = 0; mf < 4; ++mf) {
        const int m = m0 + mf * 16 + lq * 4;
#pragma unroll
        for (int nf = 0; nf < 2; ++nf) {
            const int j = j0 + wvi * 32 + nf * 16 + lr;
            const float bb = b1[j] + b2[j];
#pragma unroll
            for (int r = 0; r < 4; ++r) {
                if (m + r < M)
                    Cout[(size_t)(m + r) * 1024 + j] = acc[mf][nf][r] + bb;
            }
        }
    }
}

// ---------------------------------------------------------------------------
// Kernel 3: persistent forward-LSTM. 8 blocks x 256 threads.
// r10 tagged-record sync (proven). r11: w fragments hoisted into registers
// once (16 x bf16x8) -- removes 32 ds_read_b128 + waits from every step.
// ---------------------------------------------------------------------------
__global__ __launch_bounds__(256) void lstm_persist(
    const float* __restrict__ xg,     // [50][32][1024]
    const float* __restrict__ w_hh,   // [1024][256] row-major
    float*       __restrict__ last_f, // [32][256]
    u32x4*       __restrict__ hrec)   // [2][NREC] tagged records
{
    __shared__ __align__(16) __bf16 w_s[RWS * WPAD];   // 66 KB
    __shared__ __align__(16) __bf16 h_s[Bb * WPAD];    // 16.5 KB
    __shared__ __align__(16) float  g_s[Bb * GPAD];    // 16.5 KB
    __shared__ __align__(16) float  c_s[Bb * CPAD];    // 4.5 KB

    const int tid = threadIdx.x, blk = blockIdx.x;
    const int hs0 = blk * HS;

    for (int i = tid; i < RWS * Ee; i += 256) {
        int r = i >> 8, k = i & 255;
        int grow = (r >> 5) * Hh + hs0 + (r & 31);
        w_s[r * WPAD + k] = (__bf16)w_hh[grow * Hh + k];
    }
    for (int i = tid; i < Bb * CPAD; i += 256) c_s[i] = 0.f;
    __syncthreads();

    const int l  = tid & 63, wvi = tid >> 6;
    const int lr = l & 15,   lq  = l >> 4;
    const int b_nl = tid >> 3, jg = tid & 7;
    const int col = hs0 + jg * 4;

    // hoist static w fragments into registers (w_s dead afterwards)
    bf16x8 wB0[8], wB1[8];
#pragma unroll
    for (int kt = 0; kt < 8; ++kt) {
        int ko = kt * 32 + lq * 8;
        wB0[kt] = *(const bf16x8*)&w_s[(wvi * 32 + lr) * WPAD + ko];
        wB1[kt] = *(const bf16x8*)&w_s[(wvi * 32 + 16 + lr) * WPAD + ko];
    }

    // prefetch xg(0)
    const float* x0 = xg + (size_t)b_nl * 1024;
    f32x4 ngi = *(const f32x4*)&x0[0 * Hh + col];
    f32x4 ngf = *(const f32x4*)&x0[1 * Hh + col];
    f32x4 ngg = *(const f32x4*)&x0[2 * Hh + col];
    f32x4 ngo = *(const f32x4*)&x0[3 * Hh + col];

    for (int t = 0; t < Vv; ++t) {
        if (t > 0) {
            // ---- poll-is-load: 8 coalesced records per thread ----
            const char* hb = (const char*)hrec + (size_t)(t & 1) * RBUFB;
            const char* a0 = hb + (size_t)tid * 16;
            const char* a1 = a0 + 1 * 4096;
            const char* a2 = a0 + 2 * 4096;
            const char* a3 = a0 + 3 * 4096;
            const char* a4 = a0 + 4 * 4096;
            const char* a5 = a0 + 5 * 4096;
            const char* a6 = a0 + 6 * 4096;
            const char* a7 = a0 + 7 * 4096;
            u32x4 rc[8];
            const unsigned tt = (unsigned)t;
            int guard = 0;
            bool ok;
            do {
                asm volatile(
                    "global_load_dwordx4 %0, %8, off sc0 sc1\n\t"
                    "global_load_dwordx4 %1, %9, off sc0 sc1\n\t"
                    "global_load_dwordx4 %2, %10, off sc0 sc1\n\t"
                    "global_load_dwordx4 %3, %11, off sc0 sc1\n\t"
                    "global_load_dwordx4 %4, %12, off sc0 sc1\n\t"
                    "global_load_dwordx4 %5, %13, off sc0 sc1\n\t"
                    "global_load_dwordx4 %6, %14, off sc0 sc1\n\t"
                    "global_load_dwordx4 %7, %15, off sc0 sc1\n\t"
                    "s_waitcnt vmcnt(0)"
                    : "=&v"(rc[0]), "=&v"(rc[1]), "=&v"(rc[2]), "=&v"(rc[3]),
                      "=&v"(rc[4]), "=&v"(rc[5]), "=&v"(rc[6]), "=&v"(rc[7])
                    : "v"(a0), "v"(a1), "v"(a2), "v"(a3),
                      "v"(a4), "v"(a5), "v"(a6), "v"(a7)
                    : "memory");
                ok = true;
#pragma unroll
                for (int q = 0; q < 8; ++q)
                    ok = ok & (rc[q][0] == tt) & (rc[q][3] == tt);
            } while (!ok && ++guard < (1 << 16));

            // ---- stage payloads to LDS ----
#pragma unroll
            for (int q = 0; q < 8; ++q) {
                int rec = tid + 256 * q;
                unsigned long long pay =
                    ((unsigned long long)rc[q][2] << 32) | rc[q][1];
                *(unsigned long long*)&h_s[(rec >> 6) * WPAD + (rec & 63) * 4] = pay;
            }
            __syncthreads();   // BARRIER A: h_s ready; also fences g_s reuse

            // ---- G[32][128] = h[32][256] @ w_slice^T (w in registers) ----
            f32x4 a00 = {}, a01 = {}, a10 = {}, a11 = {};
#pragma unroll
            for (int kt = 0; kt < 8; ++kt) {
                int ko = kt * 32 + lq * 8;
                bf16x8 A0 = *(const bf16x8*)&h_s[lr * WPAD + ko];
                bf16x8 A1 = *(const bf16x8*)&h_s[(16 + lr) * WPAD + ko];
                a00 = __builtin_amdgcn_mfma_f32_16x16x32_bf16(A0, wB0[kt], a00, 0, 0, 0);
                a01 = __builtin_amdgcn_mfma_f32_16x16x32_bf16(A0, wB1[kt], a01, 0, 0, 0);
                a10 = __builtin_amdgcn_mfma_f32_16x16x32_bf16(A1, wB0[kt], a10, 0, 0, 0);
                a11 = __builtin_amdgcn_mfma_f32_16x16x32_bf16(A1, wB1[kt], a11, 0, 0, 0);
            }
#pragma unroll
            for (int r = 0; r < 4; ++r) {
                int b0 = lq * 4 + r;
                g_s[b0 * GPAD + wvi * 32 + lr]             = a00[r];
                g_s[b0 * GPAD + wvi * 32 + 16 + lr]        = a01[r];
                g_s[(16 + b0) * GPAD + wvi * 32 + lr]      = a10[r];
                g_s[(16 + b0) * GPAD + wvi * 32 + 16 + lr] = a11[r];
            }
            __syncthreads();   // BARRIER B: g_s ready
        }

        // ---- nonlinearity (prefetched xg(t)); prefetch t+1; publish ----
        {
            f32x4 gi = ngi, gf = ngf, gg = ngg, go = ngo;
            if (t + 1 < Vv) {
                const float* nx = xg + ((size_t)(t + 1) * Bb + b_nl) * 1024;
                ngi = *(const f32x4*)&nx[0 * Hh + col];
                ngf = *(const f32x4*)&nx[1 * Hh + col];
                ngg = *(const f32x4*)&nx[2 * Hh + col];
                ngo = *(const f32x4*)&nx[3 * Hh + col];
            }
            if (t > 0) {
                int gb = b_nl * GPAD + jg * 4;
                gi += *(const f32x4*)&g_s[gb + 0 * HS];
                gf += *(const f32x4*)&g_s[gb + 1 * HS];
                gg += *(const f32x4*)&g_s[gb + 2 * HS];
                go += *(const f32x4*)&g_s[gb + 3 * HS];
            }
            f32x4 cv = *(const f32x4*)&c_s[b_nl * CPAD + jg * 4];
            float hnew[4];
#pragma unroll
            for (int u = 0; u < 4; ++u) {
                float iv = sigmoidf_(gi[u]);
                float fv = sigmoidf_(gf[u]);
                float gv = tanhf_(gg[u]);
                float ov = sigmoidf_(go[u]);
                float cn = fv * cv[u] + iv * gv;
                cv[u] = cn;
                hnew[u] = ov * tanhf_(cn);
            }
            *(f32x4*)&c_s[b_nl * CPAD + jg * 4] = cv;

            if (t < Vv - 1) {
                unsigned u0 =
                    ((unsigned)__builtin_bit_cast(unsigned short, (__bf16)hnew[0])) |
                    ((unsigned)__builtin_bit_cast(unsigned short, (__bf16)hnew[1]) << 16);
                unsigned u1 =
                    ((unsigned)__builtin_bit_cast(unsigned short, (__bf16)hnew[2])) |
                    ((unsigned)__builtin_bit_cast(unsigned short, (__bf16)hnew[3]) << 16);
                const unsigned tt1 = (unsigned)(t + 1);
                u32x4 outrec;
                outrec[0] = tt1; outrec[1] = u0; outrec[2] = u1; outrec[3] = tt1;
                char* dst = (char*)hrec + (size_t)((t + 1) & 1) * RBUFB
                          + (size_t)(b_nl * 64 + blk * 8 + jg) * 16;
                asm volatile("global_store_dwordx4 %0, %1, off sc0 sc1"
                             :: "v"(dst), "v"(outrec) : "memory");
            } else {
                f32x4 hv = {hnew[0], hnew[1], hnew[2], hnew[3]};
                *(f32x4*)&last_f[b_nl * Hh + hs0 + jg * 4] = hv;
            }
        }
        // no end-of-iteration barrier: the next poll gates progress
    }
}

// ---------------------------------------------------------------------------
// Kernel 4: tail — backward single cell + head + softmax.
// ---------------------------------------------------------------------------
__global__ __launch_bounds__(512) void lstm_tail(
    const float* __restrict__ last_f,
    const float* __restrict__ xgb,
    const float* __restrict__ W_out,
    const float* __restrict__ b_out,
    float*       __restrict__ out)
{
    __shared__ float last_s[2 * Hh];
    __shared__ float logits_s[Ll];
    const int b = blockIdx.x, tid = threadIdx.x;

    if (tid < Hh) {
        last_s[tid] = last_f[b * Hh + tid];
    } else {
        int j = tid - Hh;
        float ig = sigmoidf_(xgb[b * 1024 + j]);
        float gg = tanhf_(xgb[b * 1024 + 2 * Hh + j]);
        float og = sigmoidf_(xgb[b * 1024 + 3 * Hh + j]);
        last_s[Hh + j] = og * tanhf_(ig * gg);
    }
    __syncthreads();

    if (tid < Ll) {
        float acc = b_out[tid];
        for (int q = 0; q < 2 * Hh; ++q)
            acc = fmaf(last_s[q], W_out[tid * 2 * Hh + q], acc);
        logits_s[tid] = acc;
    }
    __syncthreads();
    if (tid == 0) {
        float mx = -3.0e38f;
        for (int i = 0; i < Ll; ++i) mx = fmaxf(mx, logits_s[i]);
        float ex[Ll], s = 0.f;
        for (int i = 0; i < Ll; ++i) { ex[i] = __expf(logits_s[i] - mx); s += ex[i]; }
        float inv = 1.0f / s;
        for (int i = 0; i < Ll; ++i) out[b * Ll + i] = ex[i] * inv;
    }
}

// ---------------------------------------------------------------------------
extern "C" void kernel_launch(void* const* d_in, const int* in_sizes, int n_in,
                              void* d_out, int out_size, void* d_ws, size_t ws_size,
                              hipStream_t stream) {
    const int*   codes     = (const int*)  d_in[0];
    const float* mask      = (const float*)d_in[1];
    const float* tvals     = (const float*)d_in[2];
    const float* emb_table = (const float*)d_in[4];
    const float* WQ1       = (const float*)d_in[5];
    const float* WK1       = (const float*)d_in[6];
    const float* decay     = (const float*)d_in[7];
    const float* initial   = (const float*)d_in[8];
    const float* w_ih_f    = (const float*)d_in[9];
    const float* w_hh_f    = (const float*)d_in[10];
    const float* b_ih_f    = (const float*)d_in[11];
    const float* b_hh_f    = (const float*)d_in[12];
    const float* w_ih_b    = (const float*)d_in[13];
    // d_in[14] = w_hh_b: unused (backward output = first scan step, h0=c0=0)
    const float* b_ih_b    = (const float*)d_in[15];
    const float* b_hh_b    = (const float*)d_in[16];
    const float* W_out     = (const float*)d_in[17];
    const float* b_out     = (const float*)d_in[18];
    float* out = (float*)d_out;

    // workspace layout
    float* ws      = (float*)d_ws;
    float* vv      = ws;                 // 409600 f
    float* xg_f    = vv + 409600;        // 1638400 f
    float* xgb     = xg_f + 1638400;     // 32768 f
    float* last_f  = xgb + 32768;        // 8192 f
    __bf16* wqhi   = (__bf16*)(last_f + 8192);
    __bf16* wqlo   = wqhi + 32768;
    __bf16* wkhi   = wqlo + 32768;
    __bf16* wklo   = wkhi + 32768;
    u32x4* hrec    = (u32x4*)(wklo + 32768);   // 2*NREC records = 64 KB
    // total ~8.7 MB

    wsplit<<<256, 256, 0, stream>>>(WQ1, WK1, wqhi, wqlo, wkhi, wklo, hrec);
    attn_v2<<<BVn, 256, 0, stream>>>(codes, mask, tvals, emb_table,
                                     wqhi, wqlo, wkhi, wklo,
                                     decay, initial, vv);
    xw_mfma<<<dim3(26, 8), 256, 0, stream>>>(vv, w_ih_f, b_ih_f, b_hh_f,
                                             w_ih_b, b_ih_b, b_hh_b,
                                             xg_f, xgb);
    lstm_persist<<<NB, 256, 0, stream>>>(xg_f, w_hh_f, last_f, hrec);
    lstm_tail<<<Bb, 512, 0, stream>>>(last_f, xgb, W_out, b_out, out);
}

// Round 14
// 272.356 us; speedup vs baseline: 1.4297x; 1.0006x over previous
//
#include <hip/hip_runtime.h>
#include <hip/hip_bf16.h>
#include <math.h>

// Problem constants (from reference)
#define Bb 32
#define Vv 50
#define Cc 64
#define Ee 256
#define Aa 128
#define Hh 256
#define Ll 10
#define BVn (Bb*Vv)          // 1600
#define SCALE 0.08838834764831845f   // 1/sqrt(128)

// persistent-LSTM config
#define NB 8          // blocks
#define HS 32         // hidden units per block
#define RWS (4*HS)    // gate rows per block = 128
#define WPAD 264      // bf16 row stride
#define GPAD 132      // f32 row stride for gates scratch
#define CPAD 36       // f32 row stride for c state
#define NREC 2048     // records per parity buffer (32 batch x 64)
#define RBUFB 32768   // bytes per parity buffer (NREC*16)

// attn LDS strides (bf16 elements)
#define EPAD 264
#define QPAD 136

typedef __bf16 bf16x8 __attribute__((ext_vector_type(8)));
typedef float  f32x4  __attribute__((ext_vector_type(4)));
typedef unsigned u32x4 __attribute__((ext_vector_type(4)));

__device__ __forceinline__ float sigmoidf_(float x) {
    return 1.0f / (1.0f + __expf(-x));
}
__device__ __forceinline__ float tanhf_(float x) {
    return 1.0f - 2.0f / (__expf(2.0f * x) + 1.0f);
}

// split 8 consecutive f32 at p into bf16 hi/lo fragments
__device__ __forceinline__ void split8(const float* __restrict__ p,
                                       bf16x8& hi, bf16x8& lo) {
    f32x4 a = *(const f32x4*)p;
    f32x4 b = *(const f32x4*)(p + 4);
#pragma unroll
    for (int u = 0; u < 4; ++u) {
        __bf16 h0 = (__bf16)a[u];
        hi[u] = h0; lo[u] = (__bf16)(a[u] - (float)h0);
        __bf16 h1 = (__bf16)b[u];
        hi[4 + u] = h1; lo[4 + u] = (__bf16)(b[u] - (float)h1);
    }
}

// ---------------------------------------------------------------------------
// Kernel 0: decompose WQ1/WK1 into bf16 hi/lo pairs; blocks 0..15 zero the
// tagged h-record buffer (bypass stores -> visible to lstm's bypass reads).
// ---------------------------------------------------------------------------
__global__ __launch_bounds__(256) void wsplit(
    const float* __restrict__ wq, const float* __restrict__ wk,
    __bf16* __restrict__ qh, __bf16* __restrict__ ql,
    __bf16* __restrict__ kh, __bf16* __restrict__ kl,
    u32x4* __restrict__ hrec)
{
    if (blockIdx.x < 16) {
        int g = blockIdx.x * 256 + threadIdx.x;   // 0..4095 -> 64 KB
        u32x4 z = {0u, 0u, 0u, 0u};
        char* dst = (char*)hrec + (size_t)g * 16;
        asm volatile("global_store_dwordx4 %0, %1, off sc0 sc1"
                     :: "v"(dst), "v"(z) : "memory");
    }
    int i = blockIdx.x * 256 + threadIdx.x;    // 0..65535
    if (i < 32768) {
        float f = wq[i];
        __bf16 h = (__bf16)f;
        qh[i] = h; ql[i] = (__bf16)(f - (float)h);
    } else {
        int j = i - 32768;
        float f = wk[j];
        __bf16 h = (__bf16)f;
        kh[j] = h; kl[j] = (__bf16)(f - (float)h);
    }
}

// ---------------------------------------------------------------------------
// Kernel 1: attention — split-bf16 MFMA, in-register softmax.
// float4-vectorized emb gather (packed u64 hi/lo LDS stores);
// phase-1 kt loop unrolled x2 for load/MFMA pipelining.
// ---------------------------------------------------------------------------
__global__ __launch_bounds__(256, 2) void attn_v2(
    const int*   __restrict__ codes,
    const float* __restrict__ mask,
    const float* __restrict__ tvals,
    const float* __restrict__ emb_table,
    const __bf16* __restrict__ wqhi, const __bf16* __restrict__ wqlo,
    const __bf16* __restrict__ wkhi, const __bf16* __restrict__ wklo,
    const float* __restrict__ decay,
    const float* __restrict__ initial,
    float*       __restrict__ vv)
{
    __shared__ __align__(16) __bf16 buf[4 * Cc * QPAD];
    __shared__ int   codes_l[Cc];
    __shared__ float maskcol_s[Cc], coef_s[Cc], wsum_s[Cc];
    __shared__ float wpart[4][Cc];

    __bf16* ehi = buf;
    __bf16* elo = buf + Cc * EPAD;
    __bf16* qhi = buf;
    __bf16* qlo = buf + 1 * Cc * QPAD;
    __bf16* khi = buf + 2 * Cc * QPAD;
    __bf16* klo = buf + 3 * Cc * QPAD;

    const int n   = blockIdx.x;
    const int tid = threadIdx.x;
    const int b   = n / Vv;
    const int v   = n - b * Vv;
    const int wv  = tid >> 6;
    const int lane = tid & 63;
    const int lr  = lane & 15;
    const int lq  = lane >> 4;

    if (tid < Cc) {
        codes_l[tid]   = codes[n * Cc + tid];
        maskcol_s[tid] = mask[n * Cc + tid];
    }
    __syncthreads();

    // vectorized gather: 4096 float4s, pack 4 hi / 4 lo into u64 stores
    for (int i = tid; i < Cc * 64; i += 256) {
        int c = i >> 6, e4 = i & 63;
        f32x4 f = *(const f32x4*)&emb_table[(size_t)codes_l[c] * Ee + e4 * 4];
        unsigned short hh[4], ll[4];
#pragma unroll
        for (int u = 0; u < 4; ++u) {
            __bf16 h = (__bf16)f[u];
            hh[u] = __builtin_bit_cast(unsigned short, h);
            ll[u] = __builtin_bit_cast(unsigned short,
                                       (__bf16)(f[u] - (float)h));
        }
        unsigned long long hp =
            (unsigned long long)hh[0] | ((unsigned long long)hh[1] << 16) |
            ((unsigned long long)hh[2] << 32) | ((unsigned long long)hh[3] << 48);
        unsigned long long lp =
            (unsigned long long)ll[0] | ((unsigned long long)ll[1] << 16) |
            ((unsigned long long)ll[2] << 32) | ((unsigned long long)ll[3] << 48);
        *(unsigned long long*)&ehi[c * EPAD + e4 * 4] = hp;
        *(unsigned long long*)&elo[c * EPAD + e4 * 4] = lp;
    }
    if (tid < Cc) {
        int code = codes_l[tid];
        float keep = (maskcol_s[tid] == 0.0f) ? 1.0f : 0.0f;
        coef_s[tid] = keep * sigmoidf_(decay[code] * tvals[n] + initial[code]);
    }
    __syncthreads();

    const __bf16* bh = (wv < 2) ? wqhi : wkhi;
    const __bf16* bl = (wv < 2) ? wqlo : wklo;
    const int colbase = (wv & 1) * 64;

    f32x4 acc[4][4] = {};
#pragma unroll 2
    for (int kt = 0; kt < 8; ++kt) {
        const int k0 = kt * 32 + lq * 8;
        bf16x8 Ahh[4], All[4], Bhh[4], Bll[4];
#pragma unroll
        for (int mf = 0; mf < 4; ++mf) {
            Ahh[mf] = *(const bf16x8*)&ehi[(mf * 16 + lr) * EPAD + k0];
            All[mf] = *(const bf16x8*)&elo[(mf * 16 + lr) * EPAD + k0];
        }
#pragma unroll
        for (int nf = 0; nf < 4; ++nf) {
            const int row = colbase + nf * 16 + lr;
            Bhh[nf] = *(const bf16x8*)&bh[row * Ee + k0];
            Bll[nf] = *(const bf16x8*)&bl[row * Ee + k0];
        }
#pragma unroll
        for (int mf = 0; mf < 4; ++mf)
#pragma unroll
            for (int nf = 0; nf < 4; ++nf) {
                acc[mf][nf] = __builtin_amdgcn_mfma_f32_16x16x32_bf16(Ahh[mf], Bhh[nf], acc[mf][nf], 0, 0, 0);
                acc[mf][nf] = __builtin_amdgcn_mfma_f32_16x16x32_bf16(Ahh[mf], Bll[nf], acc[mf][nf], 0, 0, 0);
                acc[mf][nf] = __builtin_amdgcn_mfma_f32_16x16x32_bf16(All[mf], Bhh[nf], acc[mf][nf], 0, 0, 0);
            }
    }
    __syncthreads();

    {
        __bf16* dh = (wv < 2) ? qhi : khi;
        __bf16* dl = (wv < 2) ? qlo : klo;
#pragma unroll
        for (int mf = 0; mf < 4; ++mf)
#pragma unroll
            for (int nf = 0; nf < 4; ++nf) {
                const int colb = colbase + nf * 16 + lr;
#pragma unroll
                for (int r = 0; r < 4; ++r) {
                    const int m = mf * 16 + lq * 4 + r;
                    float q = acc[mf][nf][r];
                    __bf16 h = (__bf16)q;
                    dh[m * QPAD + colb] = h;
                    dl[m * QPAD + colb] = (__bf16)(q - (float)h);
                }
            }
    }
    __syncthreads();

    f32x4 dacc[4] = {};
#pragma unroll
    for (int kt = 0; kt < 4; ++kt) {
        const int k0 = kt * 32 + lq * 8;
        bf16x8 Ahh = *(const bf16x8*)&qhi[(wv * 16 + lr) * QPAD + k0];
        bf16x8 All = *(const bf16x8*)&qlo[(wv * 16 + lr) * QPAD + k0];
#pragma unroll
        for (int nf = 0; nf < 4; ++nf) {
            bf16x8 Bhh = *(const bf16x8*)&khi[(nf * 16 + lr) * QPAD + k0];
            bf16x8 Bll = *(const bf16x8*)&klo[(nf * 16 + lr) * QPAD + k0];
            dacc[nf] = __builtin_amdgcn_mfma_f32_16x16x32_bf16(Ahh, Bhh, dacc[nf], 0, 0, 0);
            dacc[nf] = __builtin_amdgcn_mfma_f32_16x16x32_bf16(Ahh, Bll, dacc[nf], 0, 0, 0);
            dacc[nf] = __builtin_amdgcn_mfma_f32_16x16x32_bf16(All, Bhh, dacc[nf], 0, 0, 0);
        }
    }

    float p[4][4], inv[4];
#pragma unroll
    for (int r = 0; r < 4; ++r) {
#pragma unroll
        for (int nf = 0; nf < 4; ++nf)
            p[r][nf] = (dacc[nf][r] - maskcol_s[nf * 16 + lr]) * SCALE;
        float mx = fmaxf(fmaxf(p[r][0], p[r][1]), fmaxf(p[r][2], p[r][3]));
        mx = fmaxf(mx, __shfl_xor(mx, 1));
        mx = fmaxf(mx, __shfl_xor(mx, 2));
        mx = fmaxf(mx, __shfl_xor(mx, 4));
        mx = fmaxf(mx, __shfl_xor(mx, 8));
        float s = 0.f;
#pragma unroll
        for (int nf = 0; nf < 4; ++nf) { p[r][nf] = __expf(p[r][nf] - mx); s += p[r][nf]; }
        s += __shfl_xor(s, 1);
        s += __shfl_xor(s, 2);
        s += __shfl_xor(s, 4);
        s += __shfl_xor(s, 8);
        inv[r] = 1.0f / s;
    }

    float part[4];
#pragma unroll
    for (int nf = 0; nf < 4; ++nf) {
        float a = 0.f;
#pragma unroll
        for (int r = 0; r < 4; ++r) {
            const int row = wv * 16 + lq * 4 + r;
            a = fmaf(coef_s[row] * inv[r], p[r][nf], a);
        }
        part[nf] = a;
    }
#pragma unroll
    for (int nf = 0; nf < 4; ++nf) {
        part[nf] += __shfl_xor(part[nf], 16);
        part[nf] += __shfl_xor(part[nf], 32);
    }
    if (lq == 0)
#pragma unroll
        for (int nf = 0; nf < 4; ++nf) wpart[wv][nf * 16 + lr] = part[nf];
    __syncthreads();
    if (tid < Cc)
        wsum_s[tid] = wpart[0][tid] + wpart[1][tid] + wpart[2][tid] + wpart[3][tid];
    __syncthreads();

    float a3 = 0.f;
#pragma unroll 8
    for (int d = 0; d < Cc; ++d)
        a3 = fmaf(wsum_s[d], emb_table[(size_t)codes_l[d] * Ee + tid], a3);
    vv[(v * Bb + b) * Ee + tid] = a3;
}

// ---------------------------------------------------------------------------
// Kernel 2: split-bf16 MFMA x@W^T, operands straight from global/L2.
// Grid (26, 8): bx<25 fwd 64-row tiles of vv; bx==25 bwd (last visit, M=32).
// ---------------------------------------------------------------------------
__global__ __launch_bounds__(256) void xw_mfma(
    const float* __restrict__ vv,
    const float* __restrict__ w_ih_f, const float* __restrict__ b_ih_f,
    const float* __restrict__ b_hh_f,
    const float* __restrict__ w_ih_b, const float* __restrict__ b_ih_b,
    const float* __restrict__ b_hh_b,
    float* __restrict__ xg_f, float* __restrict__ xgb)
{
    const bool bwd = (blockIdx.x == 25);
    const float* A  = bwd ? (vv + 49 * Bb * Ee) : vv;
    const float* W  = bwd ? w_ih_b : w_ih_f;
    const float* b1 = bwd ? b_ih_b : b_ih_f;
    const float* b2 = bwd ? b_hh_b : b_hh_f;
    float* Cout     = bwd ? xgb : xg_f;
    const int M     = bwd ? Bb : BVn;
    const int m0    = bwd ? 0 : blockIdx.x * 64;
    const int j0    = blockIdx.y * 128;

    const int tid = threadIdx.x;
    const int wvi = tid >> 6;
    const int lane = tid & 63;
    const int lr = lane & 15, lq = lane >> 4;

    f32x4 acc[4][2] = {};
#pragma unroll 2
    for (int kt = 0; kt < 8; ++kt) {
        const int k0 = kt * 32 + lq * 8;
        bf16x8 Ahh[4], All[4], Bhh[2], Bll[2];
#pragma unroll
        for (int mf = 0; mf < 4; ++mf) {
            int arow = m0 + mf * 16 + lr;
            if (arow >= M) arow = M - 1;            // clamp (bwd tile)
            split8(A + (size_t)arow * Ee + k0, Ahh[mf], All[mf]);
        }
#pragma unroll
        for (int nf = 0; nf < 2; ++nf) {
            const int brow = j0 + wvi * 32 + nf * 16 + lr;
            split8(W + (size_t)brow * Ee + k0, Bhh[nf], Bll[nf]);
        }
#pragma unroll
        for (int mf = 0; mf < 4; ++mf)
#pragma unroll
            for (int nf = 0; nf < 2; ++nf) {
                acc[mf][nf] = __builtin_amdgcn_mfma_f32_16x16x32_bf16(Ahh[mf], Bhh[nf], acc[mf][nf], 0, 0, 0);
                acc[mf][nf] = __builtin_amdgcn_mfma_f32_16x16x32_bf16(Ahh[mf], Bll[nf], acc[mf][nf], 0, 0, 0);
                acc[mf][nf] = __builtin_amdgcn_mfma_f32_16x16x32_bf16(All[mf], Bhh[nf], acc[mf][nf], 0, 0, 0);
            }
    }

#pragma unroll
    for (int mf = 0; mf < 4; ++mf) {
        const int m = m0 + mf * 16 + lq * 4;
#pragma unroll
        for (int nf = 0; nf < 2; ++nf) {
            const int j = j0 + wvi * 32 + nf * 16 + lr;
            const float bb = b1[j] + b2[j];
#pragma unroll
            for (int r = 0; r < 4; ++r) {
                if (m + r < M)
                    Cout[(size_t)(m + r) * 1024 + j] = acc[mf][nf][r] + bb;
            }
        }
    }
}

// ---------------------------------------------------------------------------
// Kernel 3: persistent forward-LSTM. 8 blocks x 256 threads.
// Tagged-record sync (r10-proven) + w fragments hoisted into registers.
// ---------------------------------------------------------------------------
__global__ __launch_bounds__(256) void lstm_persist(
    const float* __restrict__ xg,     // [50][32][1024]
    const float* __restrict__ w_hh,   // [1024][256] row-major
    float*       __restrict__ last_f, // [32][256]
    u32x4*       __restrict__ hrec)   // [2][NREC] tagged records
{
    __shared__ __align__(16) __bf16 w_s[RWS * WPAD];   // 66 KB
    __shared__ __align__(16) __bf16 h_s[Bb * WPAD];    // 16.5 KB
    __shared__ __align__(16) float  g_s[Bb * GPAD];    // 16.5 KB
    __shared__ __align__(16) float  c_s[Bb * CPAD];    // 4.5 KB

    const int tid = threadIdx.x, blk = blockIdx.x;
    const int hs0 = blk * HS;

    for (int i = tid; i < RWS * Ee; i += 256) {
        int r = i >> 8, k = i & 255;
        int grow = (r >> 5) * Hh + hs0 + (r & 31);
        w_s[r * WPAD + k] = (__bf16)w_hh[grow * Hh + k];
    }
    for (int i = tid; i < Bb * CPAD; i += 256) c_s[i] = 0.f;
    __syncthreads();

    const int l  = tid & 63, wvi = tid >> 6;
    const int lr = l & 15,   lq  = l >> 4;
    const int b_nl = tid >> 3, jg = tid & 7;
    const int col = hs0 + jg * 4;

    // hoist static w fragments into registers (w_s dead afterwards)
    bf16x8 wB0[8], wB1[8];
#pragma unroll
    for (int kt = 0; kt < 8; ++kt) {
        int ko = kt * 32 + lq * 8;
        wB0[kt] = *(const bf16x8*)&w_s[(wvi * 32 + lr) * WPAD + ko];
        wB1[kt] = *(const bf16x8*)&w_s[(wvi * 32 + 16 + lr) * WPAD + ko];
    }

    // prefetch xg(0)
    const float* x0 = xg + (size_t)b_nl * 1024;
    f32x4 ngi = *(const f32x4*)&x0[0 * Hh + col];
    f32x4 ngf = *(const f32x4*)&x0[1 * Hh + col];
    f32x4 ngg = *(const f32x4*)&x0[2 * Hh + col];
    f32x4 ngo = *(const f32x4*)&x0[3 * Hh + col];

    for (int t = 0; t < Vv; ++t) {
        if (t > 0) {
            // ---- poll-is-load: 8 coalesced records per thread ----
            const char* hb = (const char*)hrec + (size_t)(t & 1) * RBUFB;
            const char* a0 = hb + (size_t)tid * 16;
            const char* a1 = a0 + 1 * 4096;
            const char* a2 = a0 + 2 * 4096;
            const char* a3 = a0 + 3 * 4096;
            const char* a4 = a0 + 4 * 4096;
            const char* a5 = a0 + 5 * 4096;
            const char* a6 = a0 + 6 * 4096;
            const char* a7 = a0 + 7 * 4096;
            u32x4 rc[8];
            const unsigned tt = (unsigned)t;
            int guard = 0;
            bool ok;
            do {
                asm volatile(
                    "global_load_dwordx4 %0, %8, off sc0 sc1\n\t"
                    "global_load_dwordx4 %1, %9, off sc0 sc1\n\t"
                    "global_load_dwordx4 %2, %10, off sc0 sc1\n\t"
                    "global_load_dwordx4 %3, %11, off sc0 sc1\n\t"
                    "global_load_dwordx4 %4, %12, off sc0 sc1\n\t"
                    "global_load_dwordx4 %5, %13, off sc0 sc1\n\t"
                    "global_load_dwordx4 %6, %14, off sc0 sc1\n\t"
                    "global_load_dwordx4 %7, %15, off sc0 sc1\n\t"
                    "s_waitcnt vmcnt(0)"
                    : "=&v"(rc[0]), "=&v"(rc[1]), "=&v"(rc[2]), "=&v"(rc[3]),
                      "=&v"(rc[4]), "=&v"(rc[5]), "=&v"(rc[6]), "=&v"(rc[7])
                    : "v"(a0), "v"(a1), "v"(a2), "v"(a3),
                      "v"(a4), "v"(a5), "v"(a6), "v"(a7)
                    : "memory");
                ok = true;
#pragma unroll
                for (int q = 0; q < 8; ++q)
                    ok = ok & (rc[q][0] == tt) & (rc[q][3] == tt);
            } while (!ok && ++guard < (1 << 16));

            // ---- stage payloads to LDS ----
#pragma unroll
            for (int q = 0; q < 8; ++q) {
                int rec = tid + 256 * q;
                unsigned long long pay =
                    ((unsigned long long)rc[q][2] << 32) | rc[q][1];
                *(unsigned long long*)&h_s[(rec >> 6) * WPAD + (rec & 63) * 4] = pay;
            }
            __syncthreads();   // BARRIER A: h_s ready; also fences g_s reuse

            // ---- G[32][128] = h[32][256] @ w_slice^T (w in registers) ----
            f32x4 a00 = {}, a01 = {}, a10 = {}, a11 = {};
#pragma unroll
            for (int kt = 0; kt < 8; ++kt) {
                int ko = kt * 32 + lq * 8;
                bf16x8 A0 = *(const bf16x8*)&h_s[lr * WPAD + ko];
                bf16x8 A1 = *(const bf16x8*)&h_s[(16 + lr) * WPAD + ko];
                a00 = __builtin_amdgcn_mfma_f32_16x16x32_bf16(A0, wB0[kt], a00, 0, 0, 0);
                a01 = __builtin_amdgcn_mfma_f32_16x16x32_bf16(A0, wB1[kt], a01, 0, 0, 0);
                a10 = __builtin_amdgcn_mfma_f32_16x16x32_bf16(A1, wB0[kt], a10, 0, 0, 0);
                a11 = __builtin_amdgcn_mfma_f32_16x16x32_bf16(A1, wB1[kt], a11, 0, 0, 0);
            }
#pragma unroll
            for (int r = 0; r < 4; ++r) {
                int b0 = lq * 4 + r;
                g_s[b0 * GPAD + wvi * 32 + lr]             = a00[r];
                g_s[b0 * GPAD + wvi * 32 + 16 + lr]        = a01[r];
                g_s[(16 + b0) * GPAD + wvi * 32 + lr]      = a10[r];
                g_s[(16 + b0) * GPAD + wvi * 32 + 16 + lr] = a11[r];
            }
            __syncthreads();   // BARRIER B: g_s ready
        }

        // ---- nonlinearity (prefetched xg(t)); prefetch t+1; publish ----
        {
            f32x4 gi = ngi, gf = ngf, gg = ngg, go = ngo;
            if (t + 1 < Vv) {
                const float* nx = xg + ((size_t)(t + 1) * Bb + b_nl) * 1024;
                ngi = *(const f32x4*)&nx[0 * Hh + col];
                ngf = *(const f32x4*)&nx[1 * Hh + col];
                ngg = *(const f32x4*)&nx[2 * Hh + col];
                ngo = *(const f32x4*)&nx[3 * Hh + col];
            }
            if (t > 0) {
                int gb = b_nl * GPAD + jg * 4;
                gi += *(const f32x4*)&g_s[gb + 0 * HS];
                gf += *(const f32x4*)&g_s[gb + 1 * HS];
                gg += *(const f32x4*)&g_s[gb + 2 * HS];
                go += *(const f32x4*)&g_s[gb + 3 * HS];
            }
            f32x4 cv = *(const f32x4*)&c_s[b_nl * CPAD + jg * 4];
            float hnew[4];
#pragma unroll
            for (int u = 0; u < 4; ++u) {
                float iv = sigmoidf_(gi[u]);
                float fv = sigmoidf_(gf[u]);
                float gv = tanhf_(gg[u]);
                float ov = sigmoidf_(go[u]);
                float cn = fv * cv[u] + iv * gv;
                cv[u] = cn;
                hnew[u] = ov * tanhf_(cn);
            }
            *(f32x4*)&c_s[b_nl * CPAD + jg * 4] = cv;

            if (t < Vv - 1) {
                unsigned u0 =
                    ((unsigned)__builtin_bit_cast(unsigned short, (__bf16)hnew[0])) |
                    ((unsigned)__builtin_bit_cast(unsigned short, (__bf16)hnew[1]) << 16);
                unsigned u1 =
                    ((unsigned)__builtin_bit_cast(unsigned short, (__bf16)hnew[2])) |
                    ((unsigned)__builtin_bit_cast(unsigned short, (__bf16)hnew[3]) << 16);
                const unsigned tt1 = (unsigned)(t + 1);
                u32x4 outrec;
                outrec[0] = tt1; outrec[1] = u0; outrec[2] = u1; outrec[3] = tt1;
                char* dst = (char*)hrec + (size_t)((t + 1) & 1) * RBUFB
                          + (size_t)(b_nl * 64 + blk * 8 + jg) * 16;
                asm volatile("global_store_dwordx4 %0, %1, off sc0 sc1"
                             :: "v"(dst), "v"(outrec) : "memory");
            } else {
                f32x4 hv = {hnew[0], hnew[1], hnew[2], hnew[3]};
                *(f32x4*)&last_f[b_nl * Hh + hs0 + jg * 4] = hv;
            }
        }
        // no end-of-iteration barrier: the next poll gates progress
    }
}

// ---------------------------------------------------------------------------
// Kernel 4: tail — backward single cell + head + softmax.
// ---------------------------------------------------------------------------
__global__ __launch_bounds__(512) void lstm_tail(
    const float* __restrict__ last_f,
    const float* __restrict__ xgb,
    const float* __restrict__ W_out,
    const float* __restrict__ b_out,
    float*       __restrict__ out)
{
    __shared__ float last_s[2 * Hh];
    __shared__ float logits_s[Ll];
    const int b = blockIdx.x, tid = threadIdx.x;

    if (tid < Hh) {
        last_s[tid] = last_f[b * Hh + tid];
    } else {
        int j = tid - Hh;
        float ig = sigmoidf_(xgb[b * 1024 + j]);
        float gg = tanhf_(xgb[b * 1024 + 2 * Hh + j]);
        float og = sigmoidf_(xgb[b * 1024 + 3 * Hh + j]);
        last_s[Hh + j] = og * tanhf_(ig * gg);
    }
    __syncthreads();

    if (tid < Ll) {
        float acc = b_out[tid];
        for (int q = 0; q < 2 * Hh; ++q)
            acc = fmaf(last_s[q], W_out[tid * 2 * Hh + q], acc);
        logits_s[tid] = acc;
    }
    __syncthreads();
    if (tid == 0) {
        float mx = -3.0e38f;
        for (int i = 0; i < Ll; ++i) mx = fmaxf(mx, logits_s[i]);
        float ex[Ll], s = 0.f;
        for (int i = 0; i < Ll; ++i) { ex[i] = __expf(logits_s[i] - mx); s += ex[i]; }
        float inv = 1.0f / s;
        for (int i = 0; i < Ll; ++i) out[b * Ll + i] = ex[i] * inv;
    }
}

// ---------------------------------------------------------------------------
extern "C" void kernel_launch(void* const* d_in, const int* in_sizes, int n_in,
                              void* d_out, int out_size, void* d_ws, size_t ws_size,
                              hipStream_t stream) {
    const int*   codes     = (const int*)  d_in[0];
    const float* mask      = (const float*)d_in[1];
    const float* tvals     = (const float*)d_in[2];
    const float* emb_table = (const float*)d_in[4];
    const float* WQ1       = (const float*)d_in[5];
    const float* WK1       = (const float*)d_in[6];
    const float* decay     = (const float*)d_in[7];
    const float* initial   = (const float*)d_in[8];
    const float* w_ih_f    = (const float*)d_in[9];
    const float* w_hh_f    = (const float*)d_in[10];
    const float* b_ih_f    = (const float*)d_in[11];
    const float* b_hh_f    = (const float*)d_in[12];
    const float* w_ih_b    = (const float*)d_in[13];
    // d_in[14] = w_hh_b: unused (backward output = first scan step, h0=c0=0)
    const float* b_ih_b    = (const float*)d_in[15];
    const float* b_hh_b    = (const float*)d_in[16];
    const float* W_out     = (const float*)d_in[17];
    const float* b_out     = (const float*)d_in[18];
    float* out = (float*)d_out;

    // workspace layout
    float* ws      = (float*)d_ws;
    float* vv      = ws;                 // 409600 f
    float* xg_f    = vv + 409600;        // 1638400 f
    float* xgb     = xg_f + 1638400;     // 32768 f
    float* last_f  = xgb + 32768;        // 8192 f
    __bf16* wqhi   = (__bf16*)(last_f + 8192);
    __bf16* wqlo   = wqhi + 32768;
    __bf16* wkhi   = wqlo + 32768;
    __bf16* wklo   = wkhi + 32768;
    u32x4* hrec    = (u32x4*)(wklo + 32768);   // 2*NREC records = 64 KB
    // total ~8.7 MB

    wsplit<<<256, 256, 0, stream>>>(WQ1, WK1, wqhi, wqlo, wkhi, wklo, hrec);
    attn_v2<<<BVn, 256, 0, stream>>>(codes, mask, tvals, emb_table,
                                     wqhi, wqlo, wkhi, wklo,
                                     decay, initial, vv);
    xw_mfma<<<dim3(26, 8), 256, 0, stream>>>(vv, w_ih_f, b_ih_f, b_hh_f,
                                             w_ih_b, b_ih_b, b_hh_b,
                                             xg_f, xgb);
    lstm_persist<<<NB, 256, 0, stream>>>(xg_f, w_hh_f, last_f, hrec);
    lstm_tail<<<Bb, 512, 0, stream>>>(last_f, xgb, W_out, b_out, out);
}